// Round 6
// baseline (779.781 us; speedup 1.0000x reference)
//
#include <hip/hip_runtime.h>
#include <math.h>

#define NN 128
#define SM 129   // padded LDS stride for 128-wide f32 tiles
#define TS 132   // k3 tile stride (16B-aligned rows -> float4 LDS loads)
#define RS 132   // row-panel stride (doubles)
#define SS 17    // per-wave scratch stride (doubles)
#define SF 132   // f32 staging stride (16B-aligned rows -> float4)

typedef double d4 __attribute__((ext_vector_type(4)));

// ---------------------------------------------------------------------------
// K1 (R17): build symmetric-normalized Laplacian per graph (f32) only.
// ---------------------------------------------------------------------------
__global__ __launch_bounds__(256) void k1_lap(
    const int* __restrict__ src, const int* __restrict__ dst,
    int E, float* __restrict__ Lout) {
  extern __shared__ float sm1[];            // A[128*129] + dinv[128]
  float* A    = sm1;
  float* dinv = sm1 + NN * SM;
  const int g   = blockIdx.x;
  const int tid = threadIdx.x;

  for (int e = tid; e < NN * NN; e += 256) {
    int i = e >> 7, j = e & 127;
    A[i * SM + j] = 0.f;
  }
  __syncthreads();
  const int* s = src + (size_t)g * E;
  const int* d = dst + (size_t)g * E;
  for (int e = tid; e < E; e += 256) {
    int a = s[e], b = d[e];
    A[a * SM + b] = 1.f;     // benign races: all write 1.0
    A[b * SM + a] = 1.f;
  }
  __syncthreads();
  if (tid < NN) {
    float acc = 0.f;
    for (int j = 0; j < NN; ++j) acc += A[tid * SM + j];
    dinv[tid] = (acc > 0.f) ? (float)(1.0 / sqrt((double)acc)) : 0.f;
  }
  __syncthreads();
  float* Lg = Lout + (size_t)g * NN * NN;
  for (int e = tid; e < NN * NN; e += 256) {
    int i = e >> 7, j = e & 127;
    Lg[e] = ((i == j) ? 1.f : 0.f) - dinv[i] * dinv[j] * A[i * SM + j];
  }
}

// ---------------------------------------------------------------------------
// KPOW2 (R22): L2 = L @ L. 512 blocks (g = bid>>3, 16-row band q = bid&7).
// L staged as f32 in LDS (exact f32->f64 convert on read). 2 blocks/CU.
// ---------------------------------------------------------------------------
__global__ __launch_bounds__(512, 4) void kpow2(
    const float* __restrict__ L, double* __restrict__ L2) {
  extern __shared__ float Bs[];             // 128 x 132 f32
  const int bid = blockIdx.x;
  const int g = bid >> 3, q = bid & 7;
  const int tid = threadIdx.x;
  const int wv = tid >> 6, ln = tid & 63;
  const int m  = ln & 15, kq = ln >> 4;
  const int rb = 16 * q;                    // row-band base
  const int cb = wv;                        // column tile

  int rIdx[4], cIdx[4];
  {
    d4 z = {0.0, 0.0, 0.0, 0.0};
    d4 pr = __builtin_amdgcn_mfma_f64_16x16x4f64((double)m, 1.0, z, 0, 0, 0);
    d4 pc = __builtin_amdgcn_mfma_f64_16x16x4f64(1.0, (double)m, z, 0, 0, 0);
#pragma unroll
    for (int r = 0; r < 4; ++r) {
      rIdx[r] = ((int)(pr[r] * 0.25 + 0.5)) & 15;
      cIdx[r] = ((int)(pc[r] * 0.25 + 0.5)) & 15;
    }
  }

  const float* Lg = L + (size_t)g * NN * NN;
  for (int e4 = tid; e4 < (NN * NN) / 4; e4 += 512) {
    int i = e4 >> 5, j4 = (e4 & 31) * 4;
    *(float4*)(Bs + i * SF + j4) = *(const float4*)(Lg + i * NN + j4);
  }
  __syncthreads();

  d4 acc = {0.0, 0.0, 0.0, 0.0};
  for (int kc = 0; kc < 32; ++kc) {
    double a = (double)Bs[(rb + m) * SF + 4 * kc + kq];
    double b = (double)Bs[(4 * kc + kq) * SF + 16 * cb + m];
    acc = __builtin_amdgcn_mfma_f64_16x16x4f64(a, b, acc, 0, 0, 0);
  }
  double* out = L2 + (size_t)g * NN * NN;
#pragma unroll
  for (int r = 0; r < 4; ++r)
    out[(rb + rIdx[r]) * NN + 16 * cb + cIdx[r]] = acc[r];
}

// ---------------------------------------------------------------------------
// KPOW34 (R22): 512 blocks = g(6b) x quarter(2b) x job(1b).
// job 0: L3 = L2 @ L (B = L staged f32 in LDS); job 1: L4 = L2 @ L2
// (B = L2 from global, L2-cache-hot). 2 blocks/CU. Bit-identical numerics.
// ---------------------------------------------------------------------------
__global__ __launch_bounds__(512, 4) void kpow34(
    const float* __restrict__ L, const double* __restrict__ L2,
    double* __restrict__ L3, double* __restrict__ L4) {
  extern __shared__ float Bs[];             // 128 x 132 f32 (job0 only)
  const int bid = blockIdx.x;
  const int g = bid >> 3, q = (bid >> 1) & 3, job = bid & 1;
  const int tid = threadIdx.x;
  const int wv = tid >> 6, ln = tid & 63;
  const int m  = ln & 15, kq = ln >> 4;
  const int rb = 32 * q + 16 * (wv & 1);
  const int cb0 = 2 * (wv >> 1);

  int rIdx[4], cIdx[4];
  {
    d4 z = {0.0, 0.0, 0.0, 0.0};
    d4 pr = __builtin_amdgcn_mfma_f64_16x16x4f64((double)m, 1.0, z, 0, 0, 0);
    d4 pc = __builtin_amdgcn_mfma_f64_16x16x4f64(1.0, (double)m, z, 0, 0, 0);
#pragma unroll
    for (int r = 0; r < 4; ++r) {
      rIdx[r] = ((int)(pr[r] * 0.25 + 0.5)) & 15;
      cIdx[r] = ((int)(pc[r] * 0.25 + 0.5)) & 15;
    }
  }

  const float*  Lg  = L  + (size_t)g * NN * NN;
  const double* L2g = L2 + (size_t)g * NN * NN;
  if (job == 0) {
    for (int e4 = tid; e4 < (NN * NN) / 4; e4 += 512) {
      int i = e4 >> 5, j4 = (e4 & 31) * 4;
      *(float4*)(Bs + i * SF + j4) = *(const float4*)(Lg + i * NN + j4);
    }
  }
  __syncthreads();

  d4 acc[2];
#pragma unroll
  for (int c = 0; c < 2; ++c) {
    acc[c][0] = 0.0; acc[c][1] = 0.0; acc[c][2] = 0.0; acc[c][3] = 0.0;
  }
  if (job == 0) {
    for (int kc = 0; kc < 32; ++kc) {
      double a = L2g[(rb + m) * NN + 4 * kc + kq];
#pragma unroll
      for (int c = 0; c < 2; ++c) {
        double b = (double)Bs[(4 * kc + kq) * SF + 16 * (cb0 + c) + m];
        acc[c] = __builtin_amdgcn_mfma_f64_16x16x4f64(a, b, acc[c], 0, 0, 0);
      }
    }
  } else {
    for (int kc = 0; kc < 32; ++kc) {
      double a = L2g[(rb + m) * NN + 4 * kc + kq];
#pragma unroll
      for (int c = 0; c < 2; ++c) {
        double b = L2g[(4 * kc + kq) * NN + 16 * (cb0 + c) + m];
        acc[c] = __builtin_amdgcn_mfma_f64_16x16x4f64(a, b, acc[c], 0, 0, 0);
      }
    }
  }
  double* out = (job == 0 ? L3 : L4) + (size_t)g * NN * NN;
#pragma unroll
  for (int c = 0; c < 2; ++c)
#pragma unroll
    for (int r = 0; r < 4; ++r)
      out[(rb + rIdx[r]) * NN + 16 * (cb0 + c) + cIdx[r]] = acc[c][r];
}

// ---------------------------------------------------------------------------
// K2 (R14 exact, FROZEN): algebraic assembly + blocked GJ with serial-Pi.
// 268us stable; VGPR 64 + 64 AGPR = full 128 budget at (512,4).
// R18 (dbuf pipeline), R19 (merged pivot), R21 (redundant-parallel pivot)
// ALL spilled to scratch (FETCH 800MB+, 2x slowdown). The budget has ZERO
// headroom over this exact shape. DO NOT MODIFY.
// ---------------------------------------------------------------------------
__global__ __launch_bounds__(512, 4) void k2_filter(
    const float* __restrict__ L, const double* __restrict__ L2,
    const double* __restrict__ L3, const double* __restrict__ L4,
    const float* __restrict__ C, int NF, float* __restrict__ W) {
  extern __shared__ char smraw[];
  double* Rp  = (double*)smraw;                      // row panel 16x132
  double* Scd = (double*)(smraw + 16 * RS * 8);      // 8 wave scratches 16x17
  double* Pv  = (double*)(smraw + 16 * RS * 8 + 8 * 16 * SS * 8); // Pi 16x17

  const int bid = blockIdx.x;
  const int g = bid / NF, f = bid % NF;
  const int tid = threadIdx.x;
  const int wv = tid >> 6, ln = tid & 63;
  const int m  = ln & 15, kq = ln >> 4;
  double* S = Scd + wv * 16 * SS;

  double csum = 0.0;
  for (int q = 0; q < NF; ++q) { double c = (double)C[q]; csum += c * c; }
  double cn = sqrt(csum); if (cn < 1e-12) cn = 1e-12;
  const double a4 = 6.25e-6;                         // (STEP/2)^4
  const double coef = 1.4142135623730951 * a4 * ((double)C[f] / cn);
  const float  bf = (float)((double)f * 0.1);
  const double bb = (double)bf;
  const double c3 = -4.0 * bb;
  const double c2 = 6.0 * bb * bb;
  const double c1 = -4.0 * bb * bb * bb;
  const double c0 = bb * bb * bb * bb + a4;

  int rIdx[4], cIdx[4];
  {
    d4 z = {0.0, 0.0, 0.0, 0.0};
    d4 pr = __builtin_amdgcn_mfma_f64_16x16x4f64((double)m, 1.0, z, 0, 0, 0);
    d4 pc = __builtin_amdgcn_mfma_f64_16x16x4f64(1.0, (double)m, z, 0, 0, 0);
#pragma unroll
    for (int r = 0; r < 4; ++r) {
      rIdx[r] = ((int)(pr[r] * 0.25 + 0.5)) & 15;
      cIdx[r] = ((int)(pc[r] * 0.25 + 0.5)) & 15;
    }
  }

  // phase A: assemble T (D-layout) from the power matrices -- pure n^2
  const float*  Lg  = L  + (size_t)g * NN * NN;
  const double* L2g = L2 + (size_t)g * NN * NN;
  const double* L3g = L3 + (size_t)g * NN * NN;
  const double* L4g = L4 + (size_t)g * NN * NN;
  d4 T[8];
#pragma unroll
  for (int cb = 0; cb < 8; ++cb)
#pragma unroll
    for (int r = 0; r < 4; ++r) {
      int i = 16 * wv + rIdx[r], j = 16 * cb + cIdx[r];
      int idx = i * NN + j;
      double v = L4g[idx];
      v = fma(c3, L3g[idx], v);
      v = fma(c2, L2g[idx], v);
      v = fma(c1, (double)Lg[idx], v);
      if (i == j) v += c0;
      T[cb][r] = v;
    }

  // phase 4: blocked GJ, 8 steps, 3 block-barriers each, NOT unrolled
#pragma unroll 1
  for (int t = 0; t < 8; ++t) {
    if (wv == t) {
#pragma unroll
      for (int cb = 0; cb < 8; ++cb)
#pragma unroll
        for (int r = 0; r < 4; ++r)
          Rp[rIdx[r] * RS + 16 * cb + cIdx[r]] = T[cb][r];
    }
    __syncthreads();                                 // B1 (Rp visible)

    if (wv == t) {
      double sr[4];
#pragma unroll
      for (int r = 0; r < 4; ++r) sr[r] = Rp[(4 * r + kq) * RS + 16 * t + m];
#pragma unroll
      for (int k = 0; k < 16; ++k) {
        const int kr = k >> 2, kl = k & 3;
        double pv   = __shfl(sr[kr], 16 * kl + k);
        double rowv = __shfl(sr[kr], 16 * kl + m);
        double cv[4];
#pragma unroll
        for (int r = 0; r < 4; ++r) cv[r] = __shfl(sr[r], 16 * kq + k);
        double dp = 1.0 / pv;
#pragma unroll
        for (int r = 0; r < 4; ++r) {
          int i = 4 * r + kq;
          double nv;
          if (i == k)      nv = (m == k) ? dp : rowv * dp;
          else if (m == k) nv = -cv[r] * dp;
          else             nv = fma(-(cv[r] * dp), rowv, sr[r]);
          sr[r] = nv;
        }
      }
#pragma unroll
      for (int r = 0; r < 4; ++r) Pv[(4 * r + kq) * SS + m] = sr[r];
    }
    __syncthreads();                                 // B2 (Pi visible)

#pragma unroll
    for (int cb = 0; cb < 8; ++cb) {
      if (cb != t) continue;
      if (wv == t) {
#pragma unroll
        for (int r = 0; r < 4; ++r) T[cb][r] = Pv[rIdx[r] * SS + cIdx[r]];
      } else {
#pragma unroll
        for (int r = 0; r < 4; ++r) S[rIdx[r] * SS + cIdx[r]] = T[cb][r];
        __builtin_amdgcn_wave_barrier();
        d4 ncv = {0.0, 0.0, 0.0, 0.0};
#pragma unroll
        for (int kc = 0; kc < 4; ++kc) {
          double a = S[m * SS + 4 * kc + kq];
          double b = -Pv[(4 * kc + kq) * SS + m];
          ncv = __builtin_amdgcn_mfma_f64_16x16x4f64(a, b, ncv, 0, 0, 0);
        }
        T[cb] = ncv;
        __builtin_amdgcn_wave_barrier();
#pragma unroll
        for (int r = 0; r < 4; ++r) S[rIdx[r] * SS + cIdx[r]] = T[cb][r];
      }
    }
    __builtin_amdgcn_wave_barrier();

    const double* asrc = (wv == t) ? Pv : S;
#pragma unroll
    for (int cb = 0; cb < 8; ++cb) {
      if (cb == t) continue;
      d4 acc;
      if (wv == t) { acc[0] = 0.0; acc[1] = 0.0; acc[2] = 0.0; acc[3] = 0.0; }
      else         { acc = T[cb]; }
#pragma unroll
      for (int kc = 0; kc < 4; ++kc) {
        double a = asrc[m * SS + 4 * kc + kq];
        double b = Rp[(4 * kc + kq) * RS + 16 * cb + m];
        acc = __builtin_amdgcn_mfma_f64_16x16x4f64(a, b, acc, 0, 0, 0);
      }
      T[cb] = acc;
    }
    __syncthreads();                                 // B3 (Rp/Pv reads done)
  }

  // phase 5: W += coef * K^{-1}
  float* Wg = W + (size_t)g * NN * NN;
#pragma unroll
  for (int cb = 0; cb < 8; ++cb)
#pragma unroll
    for (int r = 0; r < 4; ++r)
      atomicAdd(&Wg[(16 * wv + rIdx[r]) * NN + 16 * cb + cIdx[r]],
                (float)(coef * T[cb][r]));
}

// ---------------------------------------------------------------------------
// K3 (R23): contiguous-column thread tiles -> float4 LDS ops throughout.
// Thread (tr=tid>>4, tc=tid&15) owns rows 4tr..4tr+3, cols 8tc..8tc+7.
// Per k-iter: 1 global float4 (W) + 2 ds_read_b128 (X) for 32 FMA (was 8
// scalar ds_read_b32). yT transpose: 8 ds_write_b128 (was 64 scalar).
// Second gemm: 3 ds_read_b128 per dl (was 1 b128 + 8 b32). Same numerics.
// ---------------------------------------------------------------------------
__global__ __launch_bounds__(512, 4) void k3_fused(
    const float* __restrict__ x, const float* __restrict__ rs,
    const float* __restrict__ W, float* __restrict__ G,
    float* __restrict__ emb, int F0, int R, int DTOT, int NCH,
    float rscale) {
  extern __shared__ float sm3[];
  float* ldsX = sm3;                 // 128*132 f32: X, later yT (in place)
  float* embA = sm3 + NN * TS;       // 128 f32 emb accumulator
  const int bid = blockIdx.x;
  const int g = bid / NCH;
  const int c = bid % NCH;
  const int d0 = c * 128;
  const int tid = threadIdx.x, tr = tid >> 4, tc = tid & 15;

  const float* xg = x + (size_t)g * NN * F0;
  const float* rg = rs + (size_t)g * NN * R;
  for (int e = tid; e < NN * NN; e += 512) {
    int k = e >> 7, dl = e & 127;
    int d = d0 + dl;
    float v = 0.f;
    if (d < DTOT) v = (d < F0) ? xg[k * F0 + d] : rg[k * R + (d - F0)] * rscale;
    ldsX[k * TS + dl] = v;
  }
  if (tid < NN) embA[tid] = 0.f;
  __syncthreads();

  // first gemm: y = X - W@X, W rows streamed from global (L2-hot)
  const float* Wg = W + (size_t)g * NN * NN;
  float acc[4][8];
#pragma unroll
  for (int v = 0; v < 4; ++v)
#pragma unroll
    for (int u = 0; u < 8; ++u) acc[v][u] = 0.f;
  float4 w4 = *(const float4*)(Wg + 4 * tr);
  for (int k = 0; k < NN; ++k) {
    float4 w4n;
    if (k < NN - 1) w4n = *(const float4*)(Wg + (k + 1) * NN + 4 * tr);
    float4 xa = *(const float4*)(ldsX + k * TS + 8 * tc);
    float4 xb = *(const float4*)(ldsX + k * TS + 8 * tc + 4);
    float xv[8] = {xa.x, xa.y, xa.z, xa.w, xb.x, xb.y, xb.z, xb.w};
    float wvv[4] = {w4.x, w4.y, w4.z, w4.w};
#pragma unroll
    for (int v = 0; v < 4; ++v)
#pragma unroll
      for (int u = 0; u < 8; ++u) acc[v][u] = fmaf(wvv[v], xv[u], acc[v][u]);
    w4 = w4n;
  }
  // y = X - (W@X): subtract from staged X (cols 8tc..8tc+7 of rows 4tr+v)
#pragma unroll
  for (int v = 0; v < 4; ++v) {
    float4 sa = *(const float4*)(ldsX + (4 * tr + v) * TS + 8 * tc);
    float4 sb = *(const float4*)(ldsX + (4 * tr + v) * TS + 8 * tc + 4);
    acc[v][0] = sa.x - acc[v][0]; acc[v][1] = sa.y - acc[v][1];
    acc[v][2] = sa.z - acc[v][2]; acc[v][3] = sa.w - acc[v][3];
    acc[v][4] = sb.x - acc[v][4]; acc[v][5] = sb.y - acc[v][5];
    acc[v][6] = sb.z - acc[v][6]; acc[v][7] = sb.w - acc[v][7];
  }

  // emb partials: column sums of y via LDS atomics
#pragma unroll
  for (int u = 0; u < 8; ++u) {
    float s = acc[0][u] + acc[1][u] + acc[2][u] + acc[3][u];
    atomicAdd(&embA[8 * tc + u], s);
  }
  __syncthreads();                 // all X reads + embA adds complete

  // write yT in place over the dead X buffer (8 x ds_write_b128)
#pragma unroll
  for (int u = 0; u < 8; ++u) {
    float4 col = {acc[0][u], acc[1][u], acc[2][u], acc[3][u]};
    *(float4*)(ldsX + (8 * tc + u) * TS + 4 * tr) = col;
  }
  __syncthreads();

  // emb write (fire-and-forget, overlaps second gemm)
  if (tid < 128) {
    int d = d0 + tid;
    if (d < DTOT) emb[(size_t)g * 1152 + d] = embA[tid] * (1.f / 128.f);
  }

  // second gemm: G += y @ y^T (chunk contribution)
  float gg[4][8];
#pragma unroll
  for (int v = 0; v < 4; ++v)
#pragma unroll
    for (int u = 0; u < 8; ++u) gg[v][u] = 0.f;
  for (int dl = 0; dl < NN; ++dl) {
    float4 a4v = *(const float4*)(ldsX + dl * TS + 4 * tr);
    float4 ba = *(const float4*)(ldsX + dl * TS + 8 * tc);
    float4 bb = *(const float4*)(ldsX + dl * TS + 8 * tc + 4);
    float bv[8] = {ba.x, ba.y, ba.z, ba.w, bb.x, bb.y, bb.z, bb.w};
    float av[4] = {a4v.x, a4v.y, a4v.z, a4v.w};
#pragma unroll
    for (int v = 0; v < 4; ++v)
#pragma unroll
      for (int u = 0; u < 8; ++u) gg[v][u] = fmaf(av[v], bv[u], gg[v][u]);
  }
  float* Gg = G + (size_t)g * NN * NN;
#pragma unroll
  for (int v = 0; v < 4; ++v)
#pragma unroll
    for (int u = 0; u < 8; ++u)
      atomicAdd(&Gg[(4 * tr + v) * NN + 8 * tc + u], gg[v][u]);
}

// ---------------------------------------------------------------------------
// K45 (fused): blocks 0..63 = k4 (sp terms from G); 64..127 = k5a (cdist)
// ---------------------------------------------------------------------------
__global__ __launch_bounds__(256) void k45_fused(
    const float* __restrict__ G, double* __restrict__ spt,
    const float* __restrict__ emb, float* __restrict__ Dm, int DTOT) {
  __shared__ float inr[NN];
  __shared__ double red[4];
  const int bid = blockIdx.x, tid = threadIdx.x;
  if (bid < 64) {
    const int g = bid;
    const float* Gg = G + (size_t)g * NN * NN;
    if (tid < NN) {
      float n = sqrtf(fmaxf(Gg[tid * NN + tid], 0.f));
      inr[tid] = 1.f / fmaxf(n, 1e-12f);
    }
    __syncthreads();
    double s = 0.0;
    for (int e = tid; e < NN * NN; e += 256) {
      int i = e >> 7, j = e & 127;
      s += (double)(fabsf(Gg[e]) * inr[i] * inr[j]);
    }
    for (int off = 32; off; off >>= 1) s += __shfl_down(s, off);
    int wave = tid >> 6, lane = tid & 63;
    if (lane == 0) red[wave] = s;
    __syncthreads();
    if (tid == 0) spt[g] = -(red[0] + red[1] + red[2] + red[3]) / (double)(NN * NN);
  } else {
    const int i = bid - 64;
    const int wv = tid >> 6, l = tid & 63;
    float ei[18];
#pragma unroll
    for (int s = 0; s < 18; ++s) {
      int d = l + 64 * s;
      ei[s] = (d < DTOT) ? emb[(size_t)i * 1152 + d] : 0.f;
    }
    for (int jj = 0; jj < 16; ++jj) {
      int j = 4 * jj + wv;
      float acc = 0.f;
#pragma unroll
      for (int s = 0; s < 18; ++s) {
        int d = l + 64 * s;
        if (d < DTOT) {
          float df = ei[s] - emb[(size_t)j * 1152 + d];
          acc = fmaf(df, df, acc);
        }
      }
      for (int off = 32; off; off >>= 1) acc += __shfl_down(acc, off);
      if (l == 0) Dm[i * 64 + j] = (acc > 0.f) ? sqrtf(acc) : 0.f;
    }
  }
}

// ---------------------------------------------------------------------------
// K5b (R23): 4 waves, one class per wave (was 1 wave serially looping
// classes). Dm reads are latency-bound; this quarters the serial chain.
// ---------------------------------------------------------------------------
__global__ __launch_bounds__(256) void k5b_final(
    const float* __restrict__ Dm, const double* __restrict__ spt,
    const float* __restrict__ C, int NF,
    const int* __restrict__ ncls, float* __restrict__ out) {
  __shared__ double redH[8];     // per-wave {hl1, hl2}
  __shared__ double redS;
  const int tid = threadIdx.x;
  const int wv = tid >> 6, lane = tid & 63;
  const int nc = ncls[0];

  double hl1 = 0.0, hl2 = 0.0;
  const double beta = 1.0 / (double)nc + 1e-13;
  for (int cc = wv; cc < nc; cc += 4) {
    bool ip = (lane % nc) == cc;
    double ps = 0.0, ns = 0.0;
    for (int j = 0; j < 64; ++j) {
      double dv = (double)Dm[lane * 64 + j];
      bool jp = (j % nc) == cc;
      if (ip && jp) ps += dv;
      if (!ip && !jp) ns += dv;
    }
    for (int off = 32; off; off >>= 1) {
      ps += __shfl_down(ps, off);
      ns += __shfl_down(ns, off);
    }
    if (lane == 0) {
      int npos = 0;
      for (int q = 0; q < 64; ++q) if (q % nc == cc) npos++;
      int nneg = 64 - npos;
      hl2 += ps / ((double)npos * (double)npos);
      hl1 += -(ns / ((double)nneg * (double)nneg)) / beta;
    }
  }
  if (lane == 0) { redH[2 * wv] = hl1; redH[2 * wv + 1] = hl2; }

  if (wv == 0) {
    double spf = spt[lane] * exp(-((double)(64 - lane)) * log(64.0));
    for (int off = 32; off; off >>= 1) spf += __shfl_down(spf, off);
    if (lane == 0) redS = spf;
  }
  __syncthreads();

  if (tid == 0) {
    double h1 = redH[0] + redH[2] + redH[4] + redH[6];
    double h2 = redH[1] + redH[3] + redH[5] + redH[7];
    double l1 = 0.0, l2 = 0.0;
    for (int q = 0; q < NF; ++q) { double cv = (double)C[q]; l1 += fabs(cv); l2 += cv * cv; }
    l2 = sqrt(l2); if (l2 < 1e-12) l2 = 1e-12;
    double dims = sqrt((double)NF);
    double sc = (dims - l1 / l2) / (dims - 1.0);
    out[0] = (float)(sc + h2 + h1 + redS);
  }
}

// ---------------------------------------------------------------------------
extern "C" void kernel_launch(void* const* d_in, const int* in_sizes, int n_in,
                              void* d_out, int out_size, void* d_ws, size_t ws_size,
                              hipStream_t stream) {
  (void)n_in; (void)out_size; (void)ws_size;
  const float* x    = (const float*)d_in[0];
  const float* rs   = (const float*)d_in[1];
  const float* C    = (const float*)d_in[2];
  const int*   esrc = (const int*)d_in[3];
  const int*   edst = (const int*)d_in[4];
  const int*   ncls = (const int*)d_in[5];
  float* out = (float*)d_out;

  const int F0   = in_sizes[0] / (64 * 128);
  const int R    = in_sizes[1] / (64 * 128);
  const int NF   = in_sizes[2];
  const int E    = in_sizes[3] / 64;
  const int DTOT = F0 + R;
  const int NCH  = (DTOT + 127) / 128;
  const float rscale = (float)(1.0 / sqrt((double)R));

  char* ws = (char*)d_ws;
  size_t off = 0;
  float*  L    = (float*)(ws + off);  off += (size_t)64 * NN * NN * 4;
  float*  W    = (float*)(ws + off);  off += (size_t)64 * NN * NN * 4;
  float*  G    = (float*)(ws + off);  off += (size_t)64 * NN * NN * 4;
  double* L2d  = (double*)(ws + off); off += (size_t)64 * NN * NN * 8;
  double* L3d  = (double*)(ws + off); off += (size_t)64 * NN * NN * 8;
  double* L4d  = (double*)(ws + off); off += (size_t)64 * NN * NN * 8;
  float*  emb  = (float*)(ws + off);  off += (size_t)64 * 1152 * 4;
  double* spt  = (double*)(ws + off); off += (size_t)64 * 8;
  float*  Dm   = (float*)(ws + off);  off += (size_t)64 * 64 * 4;

  // W and G are contiguous: one memset covers both
  hipMemsetAsync(W, 0, (size_t)2 * 64 * NN * NN * 4, stream);

  const int lds1 = (NN * SM + NN) * 4;             // 66560
  const int ldsf = NN * SF * 4;                    // 67584 (f32 staging)
  const int lds2 = 16 * RS * 8 + 8 * 16 * SS * 8 + 16 * SS * 8;  // 36480
  const int lds3 = (NN * TS + NN) * 4;             // 68096 -> 2 blocks/CU
  hipFuncSetAttribute((const void*)k1_lap,    hipFuncAttributeMaxDynamicSharedMemorySize, lds1);
  hipFuncSetAttribute((const void*)kpow2,     hipFuncAttributeMaxDynamicSharedMemorySize, ldsf);
  hipFuncSetAttribute((const void*)kpow34,    hipFuncAttributeMaxDynamicSharedMemorySize, ldsf);
  hipFuncSetAttribute((const void*)k2_filter, hipFuncAttributeMaxDynamicSharedMemorySize, lds2);
  hipFuncSetAttribute((const void*)k3_fused,  hipFuncAttributeMaxDynamicSharedMemorySize, lds3);

  k1_lap<<<64, 256, lds1, stream>>>(esrc, edst, E, L);
  kpow2<<<512, 512, ldsf, stream>>>(L, L2d);
  kpow34<<<512, 512, ldsf, stream>>>(L, L2d, L3d, L4d);
  k2_filter<<<64 * NF, 512, lds2, stream>>>(L, L2d, L3d, L4d, C, NF, W);
  k3_fused<<<64 * NCH, 512, lds3, stream>>>(x, rs, W, G, emb, F0, R, DTOT, NCH, rscale);
  k45_fused<<<128, 256, 0, stream>>>(G, spt, emb, Dm, DTOT);
  k5b_final<<<1, 256, 0, stream>>>(Dm, spt, C, NF, ncls, out);
}

// Round 7
// 653.172 us; speedup vs baseline: 1.1938x; 1.1938x over previous
//
#include <hip/hip_runtime.h>
#include <math.h>

#define NN 128
#define SM 129   // padded LDS stride for 128-wide f32 tiles
#define TS 132   // k3 tile stride (16B-aligned rows -> float4 LDS loads)
#define RS 132   // row-panel stride (doubles)
#define SS 17    // per-wave scratch stride (doubles)
#define SF 132   // f32 staging stride (16B-aligned rows -> float4)
#define EP 132   // emb-partial stride (floats)

typedef double d4 __attribute__((ext_vector_type(4)));

// ---------------------------------------------------------------------------
// K1 (R17): build symmetric-normalized Laplacian per graph (f32) only.
// ---------------------------------------------------------------------------
__global__ __launch_bounds__(256) void k1_lap(
    const int* __restrict__ src, const int* __restrict__ dst,
    int E, float* __restrict__ Lout) {
  extern __shared__ float sm1[];            // A[128*129] + dinv[128]
  float* A    = sm1;
  float* dinv = sm1 + NN * SM;
  const int g   = blockIdx.x;
  const int tid = threadIdx.x;

  for (int e = tid; e < NN * NN; e += 256) {
    int i = e >> 7, j = e & 127;
    A[i * SM + j] = 0.f;
  }
  __syncthreads();
  const int* s = src + (size_t)g * E;
  const int* d = dst + (size_t)g * E;
  for (int e = tid; e < E; e += 256) {
    int a = s[e], b = d[e];
    A[a * SM + b] = 1.f;     // benign races: all write 1.0
    A[b * SM + a] = 1.f;
  }
  __syncthreads();
  if (tid < NN) {
    float acc = 0.f;
    for (int j = 0; j < NN; ++j) acc += A[tid * SM + j];
    dinv[tid] = (acc > 0.f) ? (float)(1.0 / sqrt((double)acc)) : 0.f;
  }
  __syncthreads();
  float* Lg = Lout + (size_t)g * NN * NN;
  for (int e = tid; e < NN * NN; e += 256) {
    int i = e >> 7, j = e & 127;
    Lg[e] = ((i == j) ? 1.f : 0.f) - dinv[i] * dinv[j] * A[i * SM + j];
  }
}

// ---------------------------------------------------------------------------
// KPOW2 (R22): L2 = L @ L. 512 blocks (g = bid>>3, 16-row band q = bid&7).
// L staged as f32 in LDS (exact f32->f64 convert on read). 2 blocks/CU.
// ---------------------------------------------------------------------------
__global__ __launch_bounds__(512, 4) void kpow2(
    const float* __restrict__ L, double* __restrict__ L2) {
  extern __shared__ float Bs[];             // 128 x 132 f32
  const int bid = blockIdx.x;
  const int g = bid >> 3, q = bid & 7;
  const int tid = threadIdx.x;
  const int wv = tid >> 6, ln = tid & 63;
  const int m  = ln & 15, kq = ln >> 4;
  const int rb = 16 * q;                    // row-band base
  const int cb = wv;                        // column tile

  int rIdx[4], cIdx[4];
  {
    d4 z = {0.0, 0.0, 0.0, 0.0};
    d4 pr = __builtin_amdgcn_mfma_f64_16x16x4f64((double)m, 1.0, z, 0, 0, 0);
    d4 pc = __builtin_amdgcn_mfma_f64_16x16x4f64(1.0, (double)m, z, 0, 0, 0);
#pragma unroll
    for (int r = 0; r < 4; ++r) {
      rIdx[r] = ((int)(pr[r] * 0.25 + 0.5)) & 15;
      cIdx[r] = ((int)(pc[r] * 0.25 + 0.5)) & 15;
    }
  }

  const float* Lg = L + (size_t)g * NN * NN;
  for (int e4 = tid; e4 < (NN * NN) / 4; e4 += 512) {
    int i = e4 >> 5, j4 = (e4 & 31) * 4;
    *(float4*)(Bs + i * SF + j4) = *(const float4*)(Lg + i * NN + j4);
  }
  __syncthreads();

  d4 acc = {0.0, 0.0, 0.0, 0.0};
  for (int kc = 0; kc < 32; ++kc) {
    double a = (double)Bs[(rb + m) * SF + 4 * kc + kq];
    double b = (double)Bs[(4 * kc + kq) * SF + 16 * cb + m];
    acc = __builtin_amdgcn_mfma_f64_16x16x4f64(a, b, acc, 0, 0, 0);
  }
  double* out = L2 + (size_t)g * NN * NN;
#pragma unroll
  for (int r = 0; r < 4; ++r)
    out[(rb + rIdx[r]) * NN + 16 * cb + cIdx[r]] = acc[r];
}

// ---------------------------------------------------------------------------
// KPOW34 (R22): 512 blocks = g(6b) x quarter(2b) x job(1b).
// job 0: L3 = L2 @ L (B = L staged f32 in LDS); job 1: L4 = L2 @ L2
// (B = L2 from global, L2-cache-hot). 2 blocks/CU. Bit-identical numerics.
// ---------------------------------------------------------------------------
__global__ __launch_bounds__(512, 4) void kpow34(
    const float* __restrict__ L, const double* __restrict__ L2,
    double* __restrict__ L3, double* __restrict__ L4) {
  extern __shared__ float Bs[];             // 128 x 132 f32 (job0 only)
  const int bid = blockIdx.x;
  const int g = bid >> 3, q = (bid >> 1) & 3, job = bid & 1;
  const int tid = threadIdx.x;
  const int wv = tid >> 6, ln = tid & 63;
  const int m  = ln & 15, kq = ln >> 4;
  const int rb = 32 * q + 16 * (wv & 1);
  const int cb0 = 2 * (wv >> 1);

  int rIdx[4], cIdx[4];
  {
    d4 z = {0.0, 0.0, 0.0, 0.0};
    d4 pr = __builtin_amdgcn_mfma_f64_16x16x4f64((double)m, 1.0, z, 0, 0, 0);
    d4 pc = __builtin_amdgcn_mfma_f64_16x16x4f64(1.0, (double)m, z, 0, 0, 0);
#pragma unroll
    for (int r = 0; r < 4; ++r) {
      rIdx[r] = ((int)(pr[r] * 0.25 + 0.5)) & 15;
      cIdx[r] = ((int)(pc[r] * 0.25 + 0.5)) & 15;
    }
  }

  const float*  Lg  = L  + (size_t)g * NN * NN;
  const double* L2g = L2 + (size_t)g * NN * NN;
  if (job == 0) {
    for (int e4 = tid; e4 < (NN * NN) / 4; e4 += 512) {
      int i = e4 >> 5, j4 = (e4 & 31) * 4;
      *(float4*)(Bs + i * SF + j4) = *(const float4*)(Lg + i * NN + j4);
    }
  }
  __syncthreads();

  d4 acc[2];
#pragma unroll
  for (int c = 0; c < 2; ++c) {
    acc[c][0] = 0.0; acc[c][1] = 0.0; acc[c][2] = 0.0; acc[c][3] = 0.0;
  }
  if (job == 0) {
    for (int kc = 0; kc < 32; ++kc) {
      double a = L2g[(rb + m) * NN + 4 * kc + kq];
#pragma unroll
      for (int c = 0; c < 2; ++c) {
        double b = (double)Bs[(4 * kc + kq) * SF + 16 * (cb0 + c) + m];
        acc[c] = __builtin_amdgcn_mfma_f64_16x16x4f64(a, b, acc[c], 0, 0, 0);
      }
    }
  } else {
    for (int kc = 0; kc < 32; ++kc) {
      double a = L2g[(rb + m) * NN + 4 * kc + kq];
#pragma unroll
      for (int c = 0; c < 2; ++c) {
        double b = L2g[(4 * kc + kq) * NN + 16 * (cb0 + c) + m];
        acc[c] = __builtin_amdgcn_mfma_f64_16x16x4f64(a, b, acc[c], 0, 0, 0);
      }
    }
  }
  double* out = (job == 0 ? L3 : L4) + (size_t)g * NN * NN;
#pragma unroll
  for (int c = 0; c < 2; ++c)
#pragma unroll
    for (int r = 0; r < 4; ++r)
      out[(rb + rIdx[r]) * NN + 16 * (cb0 + c) + cIdx[r]] = acc[c][r];
}

// ---------------------------------------------------------------------------
// K2 (R14 exact, FROZEN): algebraic assembly + blocked GJ with serial-Pi.
// 268us stable; VGPR 64 + 64 AGPR = full 128 budget at (512,4).
// R18/R19/R21 restructurings ALL spilled to scratch. DO NOT MODIFY.
// ---------------------------------------------------------------------------
__global__ __launch_bounds__(512, 4) void k2_filter(
    const float* __restrict__ L, const double* __restrict__ L2,
    const double* __restrict__ L3, const double* __restrict__ L4,
    const float* __restrict__ C, int NF, float* __restrict__ W) {
  extern __shared__ char smraw[];
  double* Rp  = (double*)smraw;                      // row panel 16x132
  double* Scd = (double*)(smraw + 16 * RS * 8);      // 8 wave scratches 16x17
  double* Pv  = (double*)(smraw + 16 * RS * 8 + 8 * 16 * SS * 8); // Pi 16x17

  const int bid = blockIdx.x;
  const int g = bid / NF, f = bid % NF;
  const int tid = threadIdx.x;
  const int wv = tid >> 6, ln = tid & 63;
  const int m  = ln & 15, kq = ln >> 4;
  double* S = Scd + wv * 16 * SS;

  double csum = 0.0;
  for (int q = 0; q < NF; ++q) { double c = (double)C[q]; csum += c * c; }
  double cn = sqrt(csum); if (cn < 1e-12) cn = 1e-12;
  const double a4 = 6.25e-6;                         // (STEP/2)^4
  const double coef = 1.4142135623730951 * a4 * ((double)C[f] / cn);
  const float  bf = (float)((double)f * 0.1);
  const double bb = (double)bf;
  const double c3 = -4.0 * bb;
  const double c2 = 6.0 * bb * bb;
  const double c1 = -4.0 * bb * bb * bb;
  const double c0 = bb * bb * bb * bb + a4;

  int rIdx[4], cIdx[4];
  {
    d4 z = {0.0, 0.0, 0.0, 0.0};
    d4 pr = __builtin_amdgcn_mfma_f64_16x16x4f64((double)m, 1.0, z, 0, 0, 0);
    d4 pc = __builtin_amdgcn_mfma_f64_16x16x4f64(1.0, (double)m, z, 0, 0, 0);
#pragma unroll
    for (int r = 0; r < 4; ++r) {
      rIdx[r] = ((int)(pr[r] * 0.25 + 0.5)) & 15;
      cIdx[r] = ((int)(pc[r] * 0.25 + 0.5)) & 15;
    }
  }

  // phase A: assemble T (D-layout) from the power matrices -- pure n^2
  const float*  Lg  = L  + (size_t)g * NN * NN;
  const double* L2g = L2 + (size_t)g * NN * NN;
  const double* L3g = L3 + (size_t)g * NN * NN;
  const double* L4g = L4 + (size_t)g * NN * NN;
  d4 T[8];
#pragma unroll
  for (int cb = 0; cb < 8; ++cb)
#pragma unroll
    for (int r = 0; r < 4; ++r) {
      int i = 16 * wv + rIdx[r], j = 16 * cb + cIdx[r];
      int idx = i * NN + j;
      double v = L4g[idx];
      v = fma(c3, L3g[idx], v);
      v = fma(c2, L2g[idx], v);
      v = fma(c1, (double)Lg[idx], v);
      if (i == j) v += c0;
      T[cb][r] = v;
    }

  // phase 4: blocked GJ, 8 steps, 3 block-barriers each, NOT unrolled
#pragma unroll 1
  for (int t = 0; t < 8; ++t) {
    if (wv == t) {
#pragma unroll
      for (int cb = 0; cb < 8; ++cb)
#pragma unroll
        for (int r = 0; r < 4; ++r)
          Rp[rIdx[r] * RS + 16 * cb + cIdx[r]] = T[cb][r];
    }
    __syncthreads();                                 // B1 (Rp visible)

    if (wv == t) {
      double sr[4];
#pragma unroll
      for (int r = 0; r < 4; ++r) sr[r] = Rp[(4 * r + kq) * RS + 16 * t + m];
#pragma unroll
      for (int k = 0; k < 16; ++k) {
        const int kr = k >> 2, kl = k & 3;
        double pv   = __shfl(sr[kr], 16 * kl + k);
        double rowv = __shfl(sr[kr], 16 * kl + m);
        double cv[4];
#pragma unroll
        for (int r = 0; r < 4; ++r) cv[r] = __shfl(sr[r], 16 * kq + k);
        double dp = 1.0 / pv;
#pragma unroll
        for (int r = 0; r < 4; ++r) {
          int i = 4 * r + kq;
          double nv;
          if (i == k)      nv = (m == k) ? dp : rowv * dp;
          else if (m == k) nv = -cv[r] * dp;
          else             nv = fma(-(cv[r] * dp), rowv, sr[r]);
          sr[r] = nv;
        }
      }
#pragma unroll
      for (int r = 0; r < 4; ++r) Pv[(4 * r + kq) * SS + m] = sr[r];
    }
    __syncthreads();                                 // B2 (Pi visible)

#pragma unroll
    for (int cb = 0; cb < 8; ++cb) {
      if (cb != t) continue;
      if (wv == t) {
#pragma unroll
        for (int r = 0; r < 4; ++r) T[cb][r] = Pv[rIdx[r] * SS + cIdx[r]];
      } else {
#pragma unroll
        for (int r = 0; r < 4; ++r) S[rIdx[r] * SS + cIdx[r]] = T[cb][r];
        __builtin_amdgcn_wave_barrier();
        d4 ncv = {0.0, 0.0, 0.0, 0.0};
#pragma unroll
        for (int kc = 0; kc < 4; ++kc) {
          double a = S[m * SS + 4 * kc + kq];
          double b = -Pv[(4 * kc + kq) * SS + m];
          ncv = __builtin_amdgcn_mfma_f64_16x16x4f64(a, b, ncv, 0, 0, 0);
        }
        T[cb] = ncv;
        __builtin_amdgcn_wave_barrier();
#pragma unroll
        for (int r = 0; r < 4; ++r) S[rIdx[r] * SS + cIdx[r]] = T[cb][r];
      }
    }
    __builtin_amdgcn_wave_barrier();

    const double* asrc = (wv == t) ? Pv : S;
#pragma unroll
    for (int cb = 0; cb < 8; ++cb) {
      if (cb == t) continue;
      d4 acc;
      if (wv == t) { acc[0] = 0.0; acc[1] = 0.0; acc[2] = 0.0; acc[3] = 0.0; }
      else         { acc = T[cb]; }
#pragma unroll
      for (int kc = 0; kc < 4; ++kc) {
        double a = asrc[m * SS + 4 * kc + kq];
        double b = Rp[(4 * kc + kq) * RS + 16 * cb + m];
        acc = __builtin_amdgcn_mfma_f64_16x16x4f64(a, b, acc, 0, 0, 0);
      }
      T[cb] = acc;
    }
    __syncthreads();                                 // B3 (Rp/Pv reads done)
  }

  // phase 5: W += coef * K^{-1}
  float* Wg = W + (size_t)g * NN * NN;
#pragma unroll
  for (int cb = 0; cb < 8; ++cb)
#pragma unroll
    for (int r = 0; r < 4; ++r)
      atomicAdd(&Wg[(16 * wv + rIdx[r]) * NN + 16 * cb + cIdx[r]],
                (float)(coef * T[cb][r]));
}

// ---------------------------------------------------------------------------
// K3 (R24): R20 access pattern (broadcast scalar LDS reads are conflict-free
// -- R23's float4 "vectorization" was a 16-way-bank-conflict regression).
// G atomics ELIMINATED: R23 counters showed 295MB HBM write-through from
// 9.4M device-scope atomicAdds (cross-XCD atomics can't stay in L2).
// Each (g,c) block now writes its partial to a private chunk Gp[c][g] with
// plain coalesced stores; k45 sums the NCH partials on read.
// ---------------------------------------------------------------------------
__global__ __launch_bounds__(512, 4) void k3_fused(
    const float* __restrict__ x, const float* __restrict__ rs,
    const float* __restrict__ W, float* __restrict__ Gp,
    float* __restrict__ emb, int F0, int R, int DTOT, int NCH,
    float rscale) {
  extern __shared__ float sm3[];
  float* ldsX = sm3;                 // 128*132 f32: X, later yT (in place)
  float* embA = sm3 + NN * TS;       // 128 f32 emb accumulator
  const int bid = blockIdx.x;
  const int g = bid / NCH;
  const int c = bid % NCH;
  const int d0 = c * 128;
  const int tid = threadIdx.x, tr = tid >> 4, tc = tid & 15;

  const float* xg = x + (size_t)g * NN * F0;
  const float* rg = rs + (size_t)g * NN * R;
  for (int e = tid; e < NN * NN; e += 512) {
    int k = e >> 7, dl = e & 127;
    int d = d0 + dl;
    float v = 0.f;
    if (d < DTOT) v = (d < F0) ? xg[k * F0 + d] : rg[k * R + (d - F0)] * rscale;
    ldsX[k * TS + dl] = v;
  }
  if (tid < NN) embA[tid] = 0.f;
  __syncthreads();

  // first gemm: y = X - W@X, W rows streamed from global (L2-hot)
  const float* Wg = W + (size_t)g * NN * NN;
  float acc[4][8];
#pragma unroll
  for (int v = 0; v < 4; ++v)
#pragma unroll
    for (int u = 0; u < 8; ++u) acc[v][u] = 0.f;
  float4 w4 = *(const float4*)(Wg + 4 * tr);
  for (int k = 0; k < NN; ++k) {
    float4 w4n;
    if (k < NN - 1) w4n = *(const float4*)(Wg + (k + 1) * NN + 4 * tr);
    float xv[8];
#pragma unroll
    for (int u = 0; u < 8; ++u) xv[u] = ldsX[k * TS + tc + 16 * u];
    float wvv[4] = {w4.x, w4.y, w4.z, w4.w};
#pragma unroll
    for (int v = 0; v < 4; ++v)
#pragma unroll
      for (int u = 0; u < 8; ++u) acc[v][u] = fmaf(wvv[v], xv[u], acc[v][u]);
    w4 = w4n;
  }
#pragma unroll
  for (int v = 0; v < 4; ++v)
#pragma unroll
    for (int u = 0; u < 8; ++u)
      acc[v][u] = ldsX[(4 * tr + v) * TS + tc + 16 * u] - acc[v][u];

  // emb partials: column sums of y via LDS atomics
#pragma unroll
  for (int u = 0; u < 8; ++u) {
    float s = acc[0][u] + acc[1][u] + acc[2][u] + acc[3][u];
    atomicAdd(&embA[tc + 16 * u], s);
  }
  __syncthreads();                 // all X reads + embA adds complete

  // write yT in place over the dead X buffer
#pragma unroll
  for (int v = 0; v < 4; ++v)
#pragma unroll
    for (int u = 0; u < 8; ++u)
      ldsX[(tc + 16 * u) * TS + 4 * tr + v] = acc[v][u];
  __syncthreads();

  // emb write (fire-and-forget, overlaps second gemm)
  if (tid < 128) {
    int d = d0 + tid;
    if (d < DTOT) emb[(size_t)g * 1152 + d] = embA[tid] * (1.f / 128.f);
  }

  // second gemm: G_c = y_c @ y_c^T (chunk contribution, plain stores)
  float gg[4][8];
#pragma unroll
  for (int v = 0; v < 4; ++v)
#pragma unroll
    for (int u = 0; u < 8; ++u) gg[v][u] = 0.f;
  for (int dl = 0; dl < NN; ++dl) {
    float4 a4v = *(const float4*)(ldsX + dl * TS + 4 * tr);
    float bv[8];
#pragma unroll
    for (int u = 0; u < 8; ++u) bv[u] = ldsX[dl * TS + tc + 16 * u];
    float av[4] = {a4v.x, a4v.y, a4v.z, a4v.w};
#pragma unroll
    for (int v = 0; v < 4; ++v)
#pragma unroll
      for (int u = 0; u < 8; ++u) gg[v][u] = fmaf(av[v], bv[u], gg[v][u]);
  }
  float* Gc = Gp + ((size_t)c * 64 + g) * NN * NN;
#pragma unroll
  for (int v = 0; v < 4; ++v)
#pragma unroll
    for (int u = 0; u < 8; ++u)
      Gc[(4 * tr + v) * NN + tc + 16 * u] = gg[v][u];
}

// ---------------------------------------------------------------------------
// K45 (R24): blocks 0..63 = k4 (sp terms, summing NCH G-partials on read);
// 64..127 = k5a (cdist).
// ---------------------------------------------------------------------------
__global__ __launch_bounds__(256) void k45_fused(
    const float* __restrict__ Gp, double* __restrict__ spt,
    const float* __restrict__ emb, float* __restrict__ Dm, int DTOT,
    int NCH) {
  __shared__ float inr[NN];
  __shared__ double red[4];
  const int bid = blockIdx.x, tid = threadIdx.x;
  if (bid < 64) {
    const int g = bid;
    const size_t cstride = (size_t)64 * NN * NN;
    const float* Gg = Gp + (size_t)g * NN * NN;
    if (tid < NN) {
      float sdiag = 0.f;
      for (int c = 0; c < NCH; ++c) sdiag += Gg[c * cstride + tid * NN + tid];
      float n = sqrtf(fmaxf(sdiag, 0.f));
      inr[tid] = 1.f / fmaxf(n, 1e-12f);
    }
    __syncthreads();
    double s = 0.0;
    for (int e = tid; e < NN * NN; e += 256) {
      int i = e >> 7, j = e & 127;
      float sv = 0.f;
      for (int c = 0; c < NCH; ++c) sv += Gg[c * cstride + e];
      s += (double)(fabsf(sv) * inr[i] * inr[j]);
    }
    for (int off = 32; off; off >>= 1) s += __shfl_down(s, off);
    int wave = tid >> 6, lane = tid & 63;
    if (lane == 0) red[wave] = s;
    __syncthreads();
    if (tid == 0) spt[g] = -(red[0] + red[1] + red[2] + red[3]) / (double)(NN * NN);
  } else {
    const int i = bid - 64;
    const int wv = tid >> 6, l = tid & 63;
    float ei[18];
#pragma unroll
    for (int s = 0; s < 18; ++s) {
      int d = l + 64 * s;
      ei[s] = (d < DTOT) ? emb[(size_t)i * 1152 + d] : 0.f;
    }
    for (int jj = 0; jj < 16; ++jj) {
      int j = 4 * jj + wv;
      float acc = 0.f;
#pragma unroll
      for (int s = 0; s < 18; ++s) {
        int d = l + 64 * s;
        if (d < DTOT) {
          float df = ei[s] - emb[(size_t)j * 1152 + d];
          acc = fmaf(df, df, acc);
        }
      }
      for (int off = 32; off; off >>= 1) acc += __shfl_down(acc, off);
      if (l == 0) Dm[i * 64 + j] = (acc > 0.f) ? sqrtf(acc) : 0.f;
    }
  }
}

// ---------------------------------------------------------------------------
// K5b (R23): 4 waves, one class per wave; spt reduce on wave 0.
// ---------------------------------------------------------------------------
__global__ __launch_bounds__(256) void k5b_final(
    const float* __restrict__ Dm, const double* __restrict__ spt,
    const float* __restrict__ C, int NF,
    const int* __restrict__ ncls, float* __restrict__ out) {
  __shared__ double redH[8];     // per-wave {hl1, hl2}
  __shared__ double redS;
  const int tid = threadIdx.x;
  const int wv = tid >> 6, lane = tid & 63;
  const int nc = ncls[0];

  double hl1 = 0.0, hl2 = 0.0;
  const double beta = 1.0 / (double)nc + 1e-13;
  for (int cc = wv; cc < nc; cc += 4) {
    bool ip = (lane % nc) == cc;
    double ps = 0.0, ns = 0.0;
    for (int j = 0; j < 64; ++j) {
      double dv = (double)Dm[lane * 64 + j];
      bool jp = (j % nc) == cc;
      if (ip && jp) ps += dv;
      if (!ip && !jp) ns += dv;
    }
    for (int off = 32; off; off >>= 1) {
      ps += __shfl_down(ps, off);
      ns += __shfl_down(ns, off);
    }
    if (lane == 0) {
      int npos = 0;
      for (int q = 0; q < 64; ++q) if (q % nc == cc) npos++;
      int nneg = 64 - npos;
      hl2 += ps / ((double)npos * (double)npos);
      hl1 += -(ns / ((double)nneg * (double)nneg)) / beta;
    }
  }
  if (lane == 0) { redH[2 * wv] = hl1; redH[2 * wv + 1] = hl2; }

  if (wv == 0) {
    double spf = spt[lane] * exp(-((double)(64 - lane)) * log(64.0));
    for (int off = 32; off; off >>= 1) spf += __shfl_down(spf, off);
    if (lane == 0) redS = spf;
  }
  __syncthreads();

  if (tid == 0) {
    double h1 = redH[0] + redH[2] + redH[4] + redH[6];
    double h2 = redH[1] + redH[3] + redH[5] + redH[7];
    double l1 = 0.0, l2 = 0.0;
    for (int q = 0; q < NF; ++q) { double cv = (double)C[q]; l1 += fabs(cv); l2 += cv * cv; }
    l2 = sqrt(l2); if (l2 < 1e-12) l2 = 1e-12;
    double dims = sqrt((double)NF);
    double sc = (dims - l1 / l2) / (dims - 1.0);
    out[0] = (float)(sc + h2 + h1 + redS);
  }
}

// ---------------------------------------------------------------------------
extern "C" void kernel_launch(void* const* d_in, const int* in_sizes, int n_in,
                              void* d_out, int out_size, void* d_ws, size_t ws_size,
                              hipStream_t stream) {
  (void)n_in; (void)out_size; (void)ws_size;
  const float* x    = (const float*)d_in[0];
  const float* rs   = (const float*)d_in[1];
  const float* C    = (const float*)d_in[2];
  const int*   esrc = (const int*)d_in[3];
  const int*   edst = (const int*)d_in[4];
  const int*   ncls = (const int*)d_in[5];
  float* out = (float*)d_out;

  const int F0   = in_sizes[0] / (64 * 128);
  const int R    = in_sizes[1] / (64 * 128);
  const int NF   = in_sizes[2];
  const int E    = in_sizes[3] / 64;
  const int DTOT = F0 + R;
  const int NCH  = (DTOT + 127) / 128;
  const float rscale = (float)(1.0 / sqrt((double)R));

  char* ws = (char*)d_ws;
  size_t off = 0;
  float*  L    = (float*)(ws + off);  off += (size_t)64 * NN * NN * 4;   // 4MB
  float*  W    = (float*)(ws + off);  off += (size_t)64 * NN * NN * 4;   // 4MB
  // Gp overlays the L2d/L3d/L4d region (dead after k2) + extension:
  // NCH x 64 x 128 x 128 f32, c-major. L2d/L3d/L4d live in its first 24MB.
  float*  Gp   = (float*)(ws + off);
  double* L2d  = (double*)(ws + off); off += (size_t)64 * NN * NN * 8;   // 8MB
  double* L3d  = (double*)(ws + off); off += (size_t)64 * NN * NN * 8;   // 8MB
  double* L4d  = (double*)(ws + off); off += (size_t)64 * NN * NN * 8;   // 8MB
  // extend past L4d so Gp has NCH*4MB total
  {
    size_t gp_bytes = (size_t)NCH * 64 * NN * NN * 4;
    size_t have = (size_t)3 * 64 * NN * NN * 8;
    if (gp_bytes > have) off += gp_bytes - have;
  }
  float*  emb  = (float*)(ws + off);  off += (size_t)64 * 1152 * 4;
  double* spt  = (double*)(ws + off); off += (size_t)64 * 8;
  float*  Dm   = (float*)(ws + off);  off += (size_t)64 * 64 * 4;

  hipMemsetAsync(W, 0, (size_t)64 * NN * NN * 4, stream);

  const int lds1 = (NN * SM + NN) * 4;             // 66560
  const int ldsf = NN * SF * 4;                    // 67584 (f32 staging)
  const int lds2 = 16 * RS * 8 + 8 * 16 * SS * 8 + 16 * SS * 8;  // 36480
  const int lds3 = (NN * TS + NN) * 4;             // 68096 -> 2 blocks/CU
  hipFuncSetAttribute((const void*)k1_lap,    hipFuncAttributeMaxDynamicSharedMemorySize, lds1);
  hipFuncSetAttribute((const void*)kpow2,     hipFuncAttributeMaxDynamicSharedMemorySize, ldsf);
  hipFuncSetAttribute((const void*)kpow34,    hipFuncAttributeMaxDynamicSharedMemorySize, ldsf);
  hipFuncSetAttribute((const void*)k2_filter, hipFuncAttributeMaxDynamicSharedMemorySize, lds2);
  hipFuncSetAttribute((const void*)k3_fused,  hipFuncAttributeMaxDynamicSharedMemorySize, lds3);

  k1_lap<<<64, 256, lds1, stream>>>(esrc, edst, E, L);
  kpow2<<<512, 512, ldsf, stream>>>(L, L2d);
  kpow34<<<512, 512, ldsf, stream>>>(L, L2d, L3d, L4d);
  k2_filter<<<64 * NF, 512, lds2, stream>>>(L, L2d, L3d, L4d, C, NF, W);
  k3_fused<<<64 * NCH, 512, lds3, stream>>>(x, rs, W, Gp, emb, F0, R, DTOT, NCH, rscale);
  k45_fused<<<128, 256, 0, stream>>>(Gp, spt, emb, Dm, DTOT, NCH);
  k5b_final<<<1, 256, 0, stream>>>(Dm, spt, C, NF, ncls, out);
}

// Round 8
// 593.194 us; speedup vs baseline: 1.3145x; 1.1011x over previous
//
#include <hip/hip_runtime.h>
#include <math.h>

#define NN 128
#define SM 129   // padded LDS stride for 128-wide f32 tiles
#define TS 132   // k3 tile stride (16B-aligned rows -> float4 LDS loads)
#define RS 132   // row-panel stride (doubles)
#define SS 17    // per-wave scratch stride (doubles)
#define SF 132   // f32 staging stride (16B-aligned rows -> float4)

typedef double d4 __attribute__((ext_vector_type(4)));

// ---------------------------------------------------------------------------
// K1 (R17): build symmetric-normalized Laplacian per graph (f32) only.
// ---------------------------------------------------------------------------
__global__ __launch_bounds__(256) void k1_lap(
    const int* __restrict__ src, const int* __restrict__ dst,
    int E, float* __restrict__ Lout) {
  extern __shared__ float sm1[];            // A[128*129] + dinv[128]
  float* A    = sm1;
  float* dinv = sm1 + NN * SM;
  const int g   = blockIdx.x;
  const int tid = threadIdx.x;

  for (int e = tid; e < NN * NN; e += 256) {
    int i = e >> 7, j = e & 127;
    A[i * SM + j] = 0.f;
  }
  __syncthreads();
  const int* s = src + (size_t)g * E;
  const int* d = dst + (size_t)g * E;
  for (int e = tid; e < E; e += 256) {
    int a = s[e], b = d[e];
    A[a * SM + b] = 1.f;     // benign races: all write 1.0
    A[b * SM + a] = 1.f;
  }
  __syncthreads();
  if (tid < NN) {
    float acc = 0.f;
    for (int j = 0; j < NN; ++j) acc += A[tid * SM + j];
    dinv[tid] = (acc > 0.f) ? (float)(1.0 / sqrt((double)acc)) : 0.f;
  }
  __syncthreads();
  float* Lg = Lout + (size_t)g * NN * NN;
  for (int e = tid; e < NN * NN; e += 256) {
    int i = e >> 7, j = e & 127;
    Lg[e] = ((i == j) ? 1.f : 0.f) - dinv[i] * dinv[j] * A[i * SM + j];
  }
}

// ---------------------------------------------------------------------------
// KPOW2 (R22): L2 = L @ L. 512 blocks (g = bid>>3, 16-row band q = bid&7).
// L staged as f32 in LDS (exact f32->f64 convert on read). 2 blocks/CU.
// ---------------------------------------------------------------------------
__global__ __launch_bounds__(512, 4) void kpow2(
    const float* __restrict__ L, double* __restrict__ L2) {
  extern __shared__ float Bs[];             // 128 x 132 f32
  const int bid = blockIdx.x;
  const int g = bid >> 3, q = bid & 7;
  const int tid = threadIdx.x;
  const int wv = tid >> 6, ln = tid & 63;
  const int m  = ln & 15, kq = ln >> 4;
  const int rb = 16 * q;                    // row-band base
  const int cb = wv;                        // column tile

  int rIdx[4], cIdx[4];
  {
    d4 z = {0.0, 0.0, 0.0, 0.0};
    d4 pr = __builtin_amdgcn_mfma_f64_16x16x4f64((double)m, 1.0, z, 0, 0, 0);
    d4 pc = __builtin_amdgcn_mfma_f64_16x16x4f64(1.0, (double)m, z, 0, 0, 0);
#pragma unroll
    for (int r = 0; r < 4; ++r) {
      rIdx[r] = ((int)(pr[r] * 0.25 + 0.5)) & 15;
      cIdx[r] = ((int)(pc[r] * 0.25 + 0.5)) & 15;
    }
  }

  const float* Lg = L + (size_t)g * NN * NN;
  for (int e4 = tid; e4 < (NN * NN) / 4; e4 += 512) {
    int i = e4 >> 5, j4 = (e4 & 31) * 4;
    *(float4*)(Bs + i * SF + j4) = *(const float4*)(Lg + i * NN + j4);
  }
  __syncthreads();

  d4 acc = {0.0, 0.0, 0.0, 0.0};
  for (int kc = 0; kc < 32; ++kc) {
    double a = (double)Bs[(rb + m) * SF + 4 * kc + kq];
    double b = (double)Bs[(4 * kc + kq) * SF + 16 * cb + m];
    acc = __builtin_amdgcn_mfma_f64_16x16x4f64(a, b, acc, 0, 0, 0);
  }
  double* out = L2 + (size_t)g * NN * NN;
#pragma unroll
  for (int r = 0; r < 4; ++r)
    out[(rb + rIdx[r]) * NN + 16 * cb + cIdx[r]] = acc[r];
}

// ---------------------------------------------------------------------------
// KPOW34 (R22): 512 blocks = g(6b) x quarter(2b) x job(1b).
// job 0: L3 = L2 @ L (B = L staged f32 in LDS); job 1: L4 = L2 @ L2
// (B = L2 from global, L2-cache-hot). 2 blocks/CU. Bit-identical numerics.
// ---------------------------------------------------------------------------
__global__ __launch_bounds__(512, 4) void kpow34(
    const float* __restrict__ L, const double* __restrict__ L2,
    double* __restrict__ L3, double* __restrict__ L4) {
  extern __shared__ float Bs[];             // 128 x 132 f32 (job0 only)
  const int bid = blockIdx.x;
  const int g = bid >> 3, q = (bid >> 1) & 3, job = bid & 1;
  const int tid = threadIdx.x;
  const int wv = tid >> 6, ln = tid & 63;
  const int m  = ln & 15, kq = ln >> 4;
  const int rb = 32 * q + 16 * (wv & 1);
  const int cb0 = 2 * (wv >> 1);

  int rIdx[4], cIdx[4];
  {
    d4 z = {0.0, 0.0, 0.0, 0.0};
    d4 pr = __builtin_amdgcn_mfma_f64_16x16x4f64((double)m, 1.0, z, 0, 0, 0);
    d4 pc = __builtin_amdgcn_mfma_f64_16x16x4f64(1.0, (double)m, z, 0, 0, 0);
#pragma unroll
    for (int r = 0; r < 4; ++r) {
      rIdx[r] = ((int)(pr[r] * 0.25 + 0.5)) & 15;
      cIdx[r] = ((int)(pc[r] * 0.25 + 0.5)) & 15;
    }
  }

  const float*  Lg  = L  + (size_t)g * NN * NN;
  const double* L2g = L2 + (size_t)g * NN * NN;
  if (job == 0) {
    for (int e4 = tid; e4 < (NN * NN) / 4; e4 += 512) {
      int i = e4 >> 5, j4 = (e4 & 31) * 4;
      *(float4*)(Bs + i * SF + j4) = *(const float4*)(Lg + i * NN + j4);
    }
  }
  __syncthreads();

  d4 acc[2];
#pragma unroll
  for (int c = 0; c < 2; ++c) {
    acc[c][0] = 0.0; acc[c][1] = 0.0; acc[c][2] = 0.0; acc[c][3] = 0.0;
  }
  if (job == 0) {
    for (int kc = 0; kc < 32; ++kc) {
      double a = L2g[(rb + m) * NN + 4 * kc + kq];
#pragma unroll
      for (int c = 0; c < 2; ++c) {
        double b = (double)Bs[(4 * kc + kq) * SF + 16 * (cb0 + c) + m];
        acc[c] = __builtin_amdgcn_mfma_f64_16x16x4f64(a, b, acc[c], 0, 0, 0);
      }
    }
  } else {
    for (int kc = 0; kc < 32; ++kc) {
      double a = L2g[(rb + m) * NN + 4 * kc + kq];
#pragma unroll
      for (int c = 0; c < 2; ++c) {
        double b = L2g[(4 * kc + kq) * NN + 16 * (cb0 + c) + m];
        acc[c] = __builtin_amdgcn_mfma_f64_16x16x4f64(a, b, acc[c], 0, 0, 0);
      }
    }
  }
  double* out = (job == 0 ? L3 : L4) + (size_t)g * NN * NN;
#pragma unroll
  for (int c = 0; c < 2; ++c)
#pragma unroll
    for (int r = 0; r < 4; ++r)
      out[(rb + rIdx[r]) * NN + 16 * (cb0 + c) + cIdx[r]] = acc[c][r];
}

// ---------------------------------------------------------------------------
// K2 (R14 exact, FROZEN): algebraic assembly + blocked GJ with serial-Pi.
// 268us stable; VGPR 64 + 64 AGPR = full 128 budget at (512,4).
// R18/R19/R21 restructurings ALL spilled to scratch. DO NOT MODIFY.
// ---------------------------------------------------------------------------
__global__ __launch_bounds__(512, 4) void k2_filter(
    const float* __restrict__ L, const double* __restrict__ L2,
    const double* __restrict__ L3, const double* __restrict__ L4,
    const float* __restrict__ C, int NF, float* __restrict__ W) {
  extern __shared__ char smraw[];
  double* Rp  = (double*)smraw;                      // row panel 16x132
  double* Scd = (double*)(smraw + 16 * RS * 8);      // 8 wave scratches 16x17
  double* Pv  = (double*)(smraw + 16 * RS * 8 + 8 * 16 * SS * 8); // Pi 16x17

  const int bid = blockIdx.x;
  const int g = bid / NF, f = bid % NF;
  const int tid = threadIdx.x;
  const int wv = tid >> 6, ln = tid & 63;
  const int m  = ln & 15, kq = ln >> 4;
  double* S = Scd + wv * 16 * SS;

  double csum = 0.0;
  for (int q = 0; q < NF; ++q) { double c = (double)C[q]; csum += c * c; }
  double cn = sqrt(csum); if (cn < 1e-12) cn = 1e-12;
  const double a4 = 6.25e-6;                         // (STEP/2)^4
  const double coef = 1.4142135623730951 * a4 * ((double)C[f] / cn);
  const float  bf = (float)((double)f * 0.1);
  const double bb = (double)bf;
  const double c3 = -4.0 * bb;
  const double c2 = 6.0 * bb * bb;
  const double c1 = -4.0 * bb * bb * bb;
  const double c0 = bb * bb * bb * bb + a4;

  int rIdx[4], cIdx[4];
  {
    d4 z = {0.0, 0.0, 0.0, 0.0};
    d4 pr = __builtin_amdgcn_mfma_f64_16x16x4f64((double)m, 1.0, z, 0, 0, 0);
    d4 pc = __builtin_amdgcn_mfma_f64_16x16x4f64(1.0, (double)m, z, 0, 0, 0);
#pragma unroll
    for (int r = 0; r < 4; ++r) {
      rIdx[r] = ((int)(pr[r] * 0.25 + 0.5)) & 15;
      cIdx[r] = ((int)(pc[r] * 0.25 + 0.5)) & 15;
    }
  }

  // phase A: assemble T (D-layout) from the power matrices -- pure n^2
  const float*  Lg  = L  + (size_t)g * NN * NN;
  const double* L2g = L2 + (size_t)g * NN * NN;
  const double* L3g = L3 + (size_t)g * NN * NN;
  const double* L4g = L4 + (size_t)g * NN * NN;
  d4 T[8];
#pragma unroll
  for (int cb = 0; cb < 8; ++cb)
#pragma unroll
    for (int r = 0; r < 4; ++r) {
      int i = 16 * wv + rIdx[r], j = 16 * cb + cIdx[r];
      int idx = i * NN + j;
      double v = L4g[idx];
      v = fma(c3, L3g[idx], v);
      v = fma(c2, L2g[idx], v);
      v = fma(c1, (double)Lg[idx], v);
      if (i == j) v += c0;
      T[cb][r] = v;
    }

  // phase 4: blocked GJ, 8 steps, 3 block-barriers each, NOT unrolled
#pragma unroll 1
  for (int t = 0; t < 8; ++t) {
    if (wv == t) {
#pragma unroll
      for (int cb = 0; cb < 8; ++cb)
#pragma unroll
        for (int r = 0; r < 4; ++r)
          Rp[rIdx[r] * RS + 16 * cb + cIdx[r]] = T[cb][r];
    }
    __syncthreads();                                 // B1 (Rp visible)

    if (wv == t) {
      double sr[4];
#pragma unroll
      for (int r = 0; r < 4; ++r) sr[r] = Rp[(4 * r + kq) * RS + 16 * t + m];
#pragma unroll
      for (int k = 0; k < 16; ++k) {
        const int kr = k >> 2, kl = k & 3;
        double pv   = __shfl(sr[kr], 16 * kl + k);
        double rowv = __shfl(sr[kr], 16 * kl + m);
        double cv[4];
#pragma unroll
        for (int r = 0; r < 4; ++r) cv[r] = __shfl(sr[r], 16 * kq + k);
        double dp = 1.0 / pv;
#pragma unroll
        for (int r = 0; r < 4; ++r) {
          int i = 4 * r + kq;
          double nv;
          if (i == k)      nv = (m == k) ? dp : rowv * dp;
          else if (m == k) nv = -cv[r] * dp;
          else             nv = fma(-(cv[r] * dp), rowv, sr[r]);
          sr[r] = nv;
        }
      }
#pragma unroll
      for (int r = 0; r < 4; ++r) Pv[(4 * r + kq) * SS + m] = sr[r];
    }
    __syncthreads();                                 // B2 (Pi visible)

#pragma unroll
    for (int cb = 0; cb < 8; ++cb) {
      if (cb != t) continue;
      if (wv == t) {
#pragma unroll
        for (int r = 0; r < 4; ++r) T[cb][r] = Pv[rIdx[r] * SS + cIdx[r]];
      } else {
#pragma unroll
        for (int r = 0; r < 4; ++r) S[rIdx[r] * SS + cIdx[r]] = T[cb][r];
        __builtin_amdgcn_wave_barrier();
        d4 ncv = {0.0, 0.0, 0.0, 0.0};
#pragma unroll
        for (int kc = 0; kc < 4; ++kc) {
          double a = S[m * SS + 4 * kc + kq];
          double b = -Pv[(4 * kc + kq) * SS + m];
          ncv = __builtin_amdgcn_mfma_f64_16x16x4f64(a, b, ncv, 0, 0, 0);
        }
        T[cb] = ncv;
        __builtin_amdgcn_wave_barrier();
#pragma unroll
        for (int r = 0; r < 4; ++r) S[rIdx[r] * SS + cIdx[r]] = T[cb][r];
      }
    }
    __builtin_amdgcn_wave_barrier();

    const double* asrc = (wv == t) ? Pv : S;
#pragma unroll
    for (int cb = 0; cb < 8; ++cb) {
      if (cb == t) continue;
      d4 acc;
      if (wv == t) { acc[0] = 0.0; acc[1] = 0.0; acc[2] = 0.0; acc[3] = 0.0; }
      else         { acc = T[cb]; }
#pragma unroll
      for (int kc = 0; kc < 4; ++kc) {
        double a = asrc[m * SS + 4 * kc + kq];
        double b = Rp[(4 * kc + kq) * RS + 16 * cb + m];
        acc = __builtin_amdgcn_mfma_f64_16x16x4f64(a, b, acc, 0, 0, 0);
      }
      T[cb] = acc;
    }
    __syncthreads();                                 // B3 (Rp/Pv reads done)
  }

  // phase 5: W += coef * K^{-1}
  float* Wg = W + (size_t)g * NN * NN;
#pragma unroll
  for (int cb = 0; cb < 8; ++cb)
#pragma unroll
    for (int r = 0; r < 4; ++r)
      atomicAdd(&Wg[(16 * wv + rIdx[r]) * NN + 16 * cb + cIdx[r]],
                (float)(coef * T[cb][r]));
}

// ---------------------------------------------------------------------------
// K3 (R24): R20 access pattern (broadcast scalar LDS reads, conflict-free).
// G atomics eliminated: each (g,c) block writes its partial to a private
// chunk Gp[c][g] with plain coalesced stores (R23 counters: 295MB HBM
// write-through from 9.4M device-scope atomics).
// ---------------------------------------------------------------------------
__global__ __launch_bounds__(512, 4) void k3_fused(
    const float* __restrict__ x, const float* __restrict__ rs,
    const float* __restrict__ W, float* __restrict__ Gp,
    float* __restrict__ emb, int F0, int R, int DTOT, int NCH,
    float rscale) {
  extern __shared__ float sm3[];
  float* ldsX = sm3;                 // 128*132 f32: X, later yT (in place)
  float* embA = sm3 + NN * TS;       // 128 f32 emb accumulator
  const int bid = blockIdx.x;
  const int g = bid / NCH;
  const int c = bid % NCH;
  const int d0 = c * 128;
  const int tid = threadIdx.x, tr = tid >> 4, tc = tid & 15;

  const float* xg = x + (size_t)g * NN * F0;
  const float* rg = rs + (size_t)g * NN * R;
  for (int e = tid; e < NN * NN; e += 512) {
    int k = e >> 7, dl = e & 127;
    int d = d0 + dl;
    float v = 0.f;
    if (d < DTOT) v = (d < F0) ? xg[k * F0 + d] : rg[k * R + (d - F0)] * rscale;
    ldsX[k * TS + dl] = v;
  }
  if (tid < NN) embA[tid] = 0.f;
  __syncthreads();

  // first gemm: y = X - W@X, W rows streamed from global (L2-hot)
  const float* Wg = W + (size_t)g * NN * NN;
  float acc[4][8];
#pragma unroll
  for (int v = 0; v < 4; ++v)
#pragma unroll
    for (int u = 0; u < 8; ++u) acc[v][u] = 0.f;
  float4 w4 = *(const float4*)(Wg + 4 * tr);
  for (int k = 0; k < NN; ++k) {
    float4 w4n;
    if (k < NN - 1) w4n = *(const float4*)(Wg + (k + 1) * NN + 4 * tr);
    float xv[8];
#pragma unroll
    for (int u = 0; u < 8; ++u) xv[u] = ldsX[k * TS + tc + 16 * u];
    float wvv[4] = {w4.x, w4.y, w4.z, w4.w};
#pragma unroll
    for (int v = 0; v < 4; ++v)
#pragma unroll
      for (int u = 0; u < 8; ++u) acc[v][u] = fmaf(wvv[v], xv[u], acc[v][u]);
    w4 = w4n;
  }
#pragma unroll
  for (int v = 0; v < 4; ++v)
#pragma unroll
    for (int u = 0; u < 8; ++u)
      acc[v][u] = ldsX[(4 * tr + v) * TS + tc + 16 * u] - acc[v][u];

  // emb partials: column sums of y via LDS atomics
#pragma unroll
  for (int u = 0; u < 8; ++u) {
    float s = acc[0][u] + acc[1][u] + acc[2][u] + acc[3][u];
    atomicAdd(&embA[tc + 16 * u], s);
  }
  __syncthreads();                 // all X reads + embA adds complete

  // write yT in place over the dead X buffer
#pragma unroll
  for (int v = 0; v < 4; ++v)
#pragma unroll
    for (int u = 0; u < 8; ++u)
      ldsX[(tc + 16 * u) * TS + 4 * tr + v] = acc[v][u];
  __syncthreads();

  // emb write (fire-and-forget, overlaps second gemm)
  if (tid < 128) {
    int d = d0 + tid;
    if (d < DTOT) emb[(size_t)g * 1152 + d] = embA[tid] * (1.f / 128.f);
  }

  // second gemm: G_c = y_c @ y_c^T (chunk contribution, plain stores)
  float gg[4][8];
#pragma unroll
  for (int v = 0; v < 4; ++v)
#pragma unroll
    for (int u = 0; u < 8; ++u) gg[v][u] = 0.f;
  for (int dl = 0; dl < NN; ++dl) {
    float4 a4v = *(const float4*)(ldsX + dl * TS + 4 * tr);
    float bv[8];
#pragma unroll
    for (int u = 0; u < 8; ++u) bv[u] = ldsX[dl * TS + tc + 16 * u];
    float av[4] = {a4v.x, a4v.y, a4v.z, a4v.w};
#pragma unroll
    for (int v = 0; v < 4; ++v)
#pragma unroll
      for (int u = 0; u < 8; ++u) gg[v][u] = fmaf(av[v], bv[u], gg[v][u]);
  }
  float* Gc = Gp + ((size_t)c * 64 + g) * NN * NN;
#pragma unroll
  for (int v = 0; v < 4; ++v)
#pragma unroll
    for (int u = 0; u < 8; ++u)
      Gc[(4 * tr + v) * NN + tc + 16 * u] = gg[v][u];
}

// ---------------------------------------------------------------------------
// KGRED (R25): dense G = sum_c Gp[c] on a FULL grid (1024 blocks, float4
// per thread). R24's mistake was doing this gather inside k45's 64-block
// k4 phase (latency-bound on 1/4 of the machine).
// ---------------------------------------------------------------------------
__global__ __launch_bounds__(256) void kgred(
    const float* __restrict__ Gp, float* __restrict__ G, int NCH) {
  const size_t cstride = (size_t)64 * NN * NN;
  size_t idx = ((size_t)blockIdx.x * 256 + threadIdx.x) * 4;
  float4 s = *(const float4*)(Gp + idx);
  for (int c = 1; c < NCH; ++c) {
    float4 v = *(const float4*)(Gp + c * cstride + idx);
    s.x += v.x; s.y += v.y; s.z += v.z; s.w += v.w;
  }
  *(float4*)(G + idx) = s;
}

// ---------------------------------------------------------------------------
// K45 (R22 form): blocks 0..63 = k4 (sp terms from dense G); 64..127 = k5a.
// ---------------------------------------------------------------------------
__global__ __launch_bounds__(256) void k45_fused(
    const float* __restrict__ G, double* __restrict__ spt,
    const float* __restrict__ emb, float* __restrict__ Dm, int DTOT) {
  __shared__ float inr[NN];
  __shared__ double red[4];
  const int bid = blockIdx.x, tid = threadIdx.x;
  if (bid < 64) {
    const int g = bid;
    const float* Gg = G + (size_t)g * NN * NN;
    if (tid < NN) {
      float n = sqrtf(fmaxf(Gg[tid * NN + tid], 0.f));
      inr[tid] = 1.f / fmaxf(n, 1e-12f);
    }
    __syncthreads();
    double s = 0.0;
    for (int e = tid; e < NN * NN; e += 256) {
      int i = e >> 7, j = e & 127;
      s += (double)(fabsf(Gg[e]) * inr[i] * inr[j]);
    }
    for (int off = 32; off; off >>= 1) s += __shfl_down(s, off);
    int wave = tid >> 6, lane = tid & 63;
    if (lane == 0) red[wave] = s;
    __syncthreads();
    if (tid == 0) spt[g] = -(red[0] + red[1] + red[2] + red[3]) / (double)(NN * NN);
  } else {
    const int i = bid - 64;
    const int wv = tid >> 6, l = tid & 63;
    float ei[18];
#pragma unroll
    for (int s = 0; s < 18; ++s) {
      int d = l + 64 * s;
      ei[s] = (d < DTOT) ? emb[(size_t)i * 1152 + d] : 0.f;
    }
    for (int jj = 0; jj < 16; ++jj) {
      int j = 4 * jj + wv;
      float acc = 0.f;
#pragma unroll
      for (int s = 0; s < 18; ++s) {
        int d = l + 64 * s;
        if (d < DTOT) {
          float df = ei[s] - emb[(size_t)j * 1152 + d];
          acc = fmaf(df, df, acc);
        }
      }
      for (int off = 32; off; off >>= 1) acc += __shfl_down(acc, off);
      if (l == 0) Dm[i * 64 + j] = (acc > 0.f) ? sqrtf(acc) : 0.f;
    }
  }
}

// ---------------------------------------------------------------------------
// K5b (R23): 4 waves, one class per wave; spt reduce on wave 0.
// ---------------------------------------------------------------------------
__global__ __launch_bounds__(256) void k5b_final(
    const float* __restrict__ Dm, const double* __restrict__ spt,
    const float* __restrict__ C, int NF,
    const int* __restrict__ ncls, float* __restrict__ out) {
  __shared__ double redH[8];     // per-wave {hl1, hl2}
  __shared__ double redS;
  const int tid = threadIdx.x;
  const int wv = tid >> 6, lane = tid & 63;
  const int nc = ncls[0];

  double hl1 = 0.0, hl2 = 0.0;
  const double beta = 1.0 / (double)nc + 1e-13;
  for (int cc = wv; cc < nc; cc += 4) {
    bool ip = (lane % nc) == cc;
    double ps = 0.0, ns = 0.0;
    for (int j = 0; j < 64; ++j) {
      double dv = (double)Dm[lane * 64 + j];
      bool jp = (j % nc) == cc;
      if (ip && jp) ps += dv;
      if (!ip && !jp) ns += dv;
    }
    for (int off = 32; off; off >>= 1) {
      ps += __shfl_down(ps, off);
      ns += __shfl_down(ns, off);
    }
    if (lane == 0) {
      int npos = 0;
      for (int q = 0; q < 64; ++q) if (q % nc == cc) npos++;
      int nneg = 64 - npos;
      hl2 += ps / ((double)npos * (double)npos);
      hl1 += -(ns / ((double)nneg * (double)nneg)) / beta;
    }
  }
  if (lane == 0) { redH[2 * wv] = hl1; redH[2 * wv + 1] = hl2; }

  if (wv == 0) {
    double spf = spt[lane] * exp(-((double)(64 - lane)) * log(64.0));
    for (int off = 32; off; off >>= 1) spf += __shfl_down(spf, off);
    if (lane == 0) redS = spf;
  }
  __syncthreads();

  if (tid == 0) {
    double h1 = redH[0] + redH[2] + redH[4] + redH[6];
    double h2 = redH[1] + redH[3] + redH[5] + redH[7];
    double l1 = 0.0, l2 = 0.0;
    for (int q = 0; q < NF; ++q) { double cv = (double)C[q]; l1 += fabs(cv); l2 += cv * cv; }
    l2 = sqrt(l2); if (l2 < 1e-12) l2 = 1e-12;
    double dims = sqrt((double)NF);
    double sc = (dims - l1 / l2) / (dims - 1.0);
    out[0] = (float)(sc + h2 + h1 + redS);
  }
}

// ---------------------------------------------------------------------------
extern "C" void kernel_launch(void* const* d_in, const int* in_sizes, int n_in,
                              void* d_out, int out_size, void* d_ws, size_t ws_size,
                              hipStream_t stream) {
  (void)n_in; (void)out_size; (void)ws_size;
  const float* x    = (const float*)d_in[0];
  const float* rs   = (const float*)d_in[1];
  const float* C    = (const float*)d_in[2];
  const int*   esrc = (const int*)d_in[3];
  const int*   edst = (const int*)d_in[4];
  const int*   ncls = (const int*)d_in[5];
  float* out = (float*)d_out;

  const int F0   = in_sizes[0] / (64 * 128);
  const int R    = in_sizes[1] / (64 * 128);
  const int NF   = in_sizes[2];
  const int E    = in_sizes[3] / 64;
  const int DTOT = F0 + R;
  const int NCH  = (DTOT + 127) / 128;
  const float rscale = (float)(1.0 / sqrt((double)R));

  char* ws = (char*)d_ws;
  size_t off = 0;
  float*  L    = (float*)(ws + off);  off += (size_t)64 * NN * NN * 4;   // 4MB; reused as dense G after k2
  float*  W    = (float*)(ws + off);  off += (size_t)64 * NN * NN * 4;   // 4MB
  // Gp overlays the L2d/L3d/L4d region (dead after k2) + extension:
  // NCH x 64 x 128 x 128 f32, c-major.
  float*  Gp   = (float*)(ws + off);
  double* L2d  = (double*)(ws + off); off += (size_t)64 * NN * NN * 8;   // 8MB
  double* L3d  = (double*)(ws + off); off += (size_t)64 * NN * NN * 8;   // 8MB
  double* L4d  = (double*)(ws + off); off += (size_t)64 * NN * NN * 8;   // 8MB
  {
    size_t gp_bytes = (size_t)NCH * 64 * NN * NN * 4;
    size_t have = (size_t)3 * 64 * NN * NN * 8;
    if (gp_bytes > have) off += gp_bytes - have;
  }
  float*  emb  = (float*)(ws + off);  off += (size_t)64 * 1152 * 4;
  double* spt  = (double*)(ws + off); off += (size_t)64 * 8;
  float*  Dm   = (float*)(ws + off);  off += (size_t)64 * 64 * 4;
  float*  G    = L;                   // dense G reuses L (dead after k2)

  hipMemsetAsync(W, 0, (size_t)64 * NN * NN * 4, stream);

  const int lds1 = (NN * SM + NN) * 4;             // 66560
  const int ldsf = NN * SF * 4;                    // 67584 (f32 staging)
  const int lds2 = 16 * RS * 8 + 8 * 16 * SS * 8 + 16 * SS * 8;  // 36480
  const int lds3 = (NN * TS + NN) * 4;             // 68096 -> 2 blocks/CU
  hipFuncSetAttribute((const void*)k1_lap,    hipFuncAttributeMaxDynamicSharedMemorySize, lds1);
  hipFuncSetAttribute((const void*)kpow2,     hipFuncAttributeMaxDynamicSharedMemorySize, ldsf);
  hipFuncSetAttribute((const void*)kpow34,    hipFuncAttributeMaxDynamicSharedMemorySize, ldsf);
  hipFuncSetAttribute((const void*)k2_filter, hipFuncAttributeMaxDynamicSharedMemorySize, lds2);
  hipFuncSetAttribute((const void*)k3_fused,  hipFuncAttributeMaxDynamicSharedMemorySize, lds3);

  k1_lap<<<64, 256, lds1, stream>>>(esrc, edst, E, L);
  kpow2<<<512, 512, ldsf, stream>>>(L, L2d);
  kpow34<<<512, 512, ldsf, stream>>>(L, L2d, L3d, L4d);
  k2_filter<<<64 * NF, 512, lds2, stream>>>(L, L2d, L3d, L4d, C, NF, W);
  k3_fused<<<64 * NCH, 512, lds3, stream>>>(x, rs, W, Gp, emb, F0, R, DTOT, NCH, rscale);
  kgred<<<1024, 256, 0, stream>>>(Gp, G, NCH);
  k45_fused<<<128, 256, 0, stream>>>(G, spt, emb, Dm, DTOT);
  k5b_final<<<1, 256, 0, stream>>>(Dm, spt, C, NF, ncls, out);
}

// Round 9
// 582.916 us; speedup vs baseline: 1.3377x; 1.0176x over previous
//
#include <hip/hip_runtime.h>
#include <math.h>

#define NN 128
#define SM 129   // padded LDS stride for 128-wide f32 tiles
#define TS 132   // k3 tile stride (16B-aligned rows -> float4 LDS loads)
#define RS 132   // row-panel stride (doubles)
#define SS 17    // per-wave scratch stride (doubles)
#define SF 132   // f32 staging stride (16B-aligned rows -> float4)

typedef double d4 __attribute__((ext_vector_type(4)));

// ---------------------------------------------------------------------------
// K1 (R17): build symmetric-normalized Laplacian per graph (f32) only.
// ---------------------------------------------------------------------------
__global__ __launch_bounds__(256) void k1_lap(
    const int* __restrict__ src, const int* __restrict__ dst,
    int E, float* __restrict__ Lout) {
  extern __shared__ float sm1[];            // A[128*129] + dinv[128]
  float* A    = sm1;
  float* dinv = sm1 + NN * SM;
  const int g   = blockIdx.x;
  const int tid = threadIdx.x;

  for (int e = tid; e < NN * NN; e += 256) {
    int i = e >> 7, j = e & 127;
    A[i * SM + j] = 0.f;
  }
  __syncthreads();
  const int* s = src + (size_t)g * E;
  const int* d = dst + (size_t)g * E;
  for (int e = tid; e < E; e += 256) {
    int a = s[e], b = d[e];
    A[a * SM + b] = 1.f;     // benign races: all write 1.0
    A[b * SM + a] = 1.f;
  }
  __syncthreads();
  if (tid < NN) {
    float acc = 0.f;
    for (int j = 0; j < NN; ++j) acc += A[tid * SM + j];
    dinv[tid] = (acc > 0.f) ? (float)(1.0 / sqrt((double)acc)) : 0.f;
  }
  __syncthreads();
  float* Lg = Lout + (size_t)g * NN * NN;
  for (int e = tid; e < NN * NN; e += 256) {
    int i = e >> 7, j = e & 127;
    Lg[e] = ((i == j) ? 1.f : 0.f) - dinv[i] * dinv[j] * A[i * SM + j];
  }
}

// ---------------------------------------------------------------------------
// KPOW2 (R22): L2 = L @ L. 512 blocks (g = bid>>3, 16-row band q = bid&7).
// L staged as f32 in LDS (exact f32->f64 convert on read). 2 blocks/CU.
// ---------------------------------------------------------------------------
__global__ __launch_bounds__(512, 4) void kpow2(
    const float* __restrict__ L, double* __restrict__ L2) {
  extern __shared__ float Bs[];             // 128 x 132 f32
  const int bid = blockIdx.x;
  const int g = bid >> 3, q = bid & 7;
  const int tid = threadIdx.x;
  const int wv = tid >> 6, ln = tid & 63;
  const int m  = ln & 15, kq = ln >> 4;
  const int rb = 16 * q;                    // row-band base
  const int cb = wv;                        // column tile

  int rIdx[4], cIdx[4];
  {
    d4 z = {0.0, 0.0, 0.0, 0.0};
    d4 pr = __builtin_amdgcn_mfma_f64_16x16x4f64((double)m, 1.0, z, 0, 0, 0);
    d4 pc = __builtin_amdgcn_mfma_f64_16x16x4f64(1.0, (double)m, z, 0, 0, 0);
#pragma unroll
    for (int r = 0; r < 4; ++r) {
      rIdx[r] = ((int)(pr[r] * 0.25 + 0.5)) & 15;
      cIdx[r] = ((int)(pc[r] * 0.25 + 0.5)) & 15;
    }
  }

  const float* Lg = L + (size_t)g * NN * NN;
  for (int e4 = tid; e4 < (NN * NN) / 4; e4 += 512) {
    int i = e4 >> 5, j4 = (e4 & 31) * 4;
    *(float4*)(Bs + i * SF + j4) = *(const float4*)(Lg + i * NN + j4);
  }
  __syncthreads();

  d4 acc = {0.0, 0.0, 0.0, 0.0};
  for (int kc = 0; kc < 32; ++kc) {
    double a = (double)Bs[(rb + m) * SF + 4 * kc + kq];
    double b = (double)Bs[(4 * kc + kq) * SF + 16 * cb + m];
    acc = __builtin_amdgcn_mfma_f64_16x16x4f64(a, b, acc, 0, 0, 0);
  }
  double* out = L2 + (size_t)g * NN * NN;
#pragma unroll
  for (int r = 0; r < 4; ++r)
    out[(rb + rIdx[r]) * NN + 16 * cb + cIdx[r]] = acc[r];
}

// ---------------------------------------------------------------------------
// KPOW34 (R22): 512 blocks = g(6b) x quarter(2b) x job(1b).
// job 0: L3 = L2 @ L (B = L staged f32 in LDS); job 1: L4 = L2 @ L2
// (B = L2 from global, L2-cache-hot). 2 blocks/CU. Bit-identical numerics.
// ---------------------------------------------------------------------------
__global__ __launch_bounds__(512, 4) void kpow34(
    const float* __restrict__ L, const double* __restrict__ L2,
    double* __restrict__ L3, double* __restrict__ L4) {
  extern __shared__ float Bs[];             // 128 x 132 f32 (job0 only)
  const int bid = blockIdx.x;
  const int g = bid >> 3, q = (bid >> 1) & 3, job = bid & 1;
  const int tid = threadIdx.x;
  const int wv = tid >> 6, ln = tid & 63;
  const int m  = ln & 15, kq = ln >> 4;
  const int rb = 32 * q + 16 * (wv & 1);
  const int cb0 = 2 * (wv >> 1);

  int rIdx[4], cIdx[4];
  {
    d4 z = {0.0, 0.0, 0.0, 0.0};
    d4 pr = __builtin_amdgcn_mfma_f64_16x16x4f64((double)m, 1.0, z, 0, 0, 0);
    d4 pc = __builtin_amdgcn_mfma_f64_16x16x4f64(1.0, (double)m, z, 0, 0, 0);
#pragma unroll
    for (int r = 0; r < 4; ++r) {
      rIdx[r] = ((int)(pr[r] * 0.25 + 0.5)) & 15;
      cIdx[r] = ((int)(pc[r] * 0.25 + 0.5)) & 15;
    }
  }

  const float*  Lg  = L  + (size_t)g * NN * NN;
  const double* L2g = L2 + (size_t)g * NN * NN;
  if (job == 0) {
    for (int e4 = tid; e4 < (NN * NN) / 4; e4 += 512) {
      int i = e4 >> 5, j4 = (e4 & 31) * 4;
      *(float4*)(Bs + i * SF + j4) = *(const float4*)(Lg + i * NN + j4);
    }
  }
  __syncthreads();

  d4 acc[2];
#pragma unroll
  for (int c = 0; c < 2; ++c) {
    acc[c][0] = 0.0; acc[c][1] = 0.0; acc[c][2] = 0.0; acc[c][3] = 0.0;
  }
  if (job == 0) {
    for (int kc = 0; kc < 32; ++kc) {
      double a = L2g[(rb + m) * NN + 4 * kc + kq];
#pragma unroll
      for (int c = 0; c < 2; ++c) {
        double b = (double)Bs[(4 * kc + kq) * SF + 16 * (cb0 + c) + m];
        acc[c] = __builtin_amdgcn_mfma_f64_16x16x4f64(a, b, acc[c], 0, 0, 0);
      }
    }
  } else {
    for (int kc = 0; kc < 32; ++kc) {
      double a = L2g[(rb + m) * NN + 4 * kc + kq];
#pragma unroll
      for (int c = 0; c < 2; ++c) {
        double b = L2g[(4 * kc + kq) * NN + 16 * (cb0 + c) + m];
        acc[c] = __builtin_amdgcn_mfma_f64_16x16x4f64(a, b, acc[c], 0, 0, 0);
      }
    }
  }
  double* out = (job == 0 ? L3 : L4) + (size_t)g * NN * NN;
#pragma unroll
  for (int c = 0; c < 2; ++c)
#pragma unroll
    for (int r = 0; r < 4; ++r)
      out[(rb + rIdx[r]) * NN + 16 * (cb0 + c) + cIdx[r]] = acc[c][r];
}

// ---------------------------------------------------------------------------
// K2 (R14 exact, FROZEN): algebraic assembly + blocked GJ with serial-Pi.
// 268us stable; VGPR 64 + 64 AGPR = full 128 budget at (512,4).
// R18/R19/R21 restructurings ALL spilled to scratch. DO NOT MODIFY.
// ---------------------------------------------------------------------------
__global__ __launch_bounds__(512, 4) void k2_filter(
    const float* __restrict__ L, const double* __restrict__ L2,
    const double* __restrict__ L3, const double* __restrict__ L4,
    const float* __restrict__ C, int NF, float* __restrict__ W) {
  extern __shared__ char smraw[];
  double* Rp  = (double*)smraw;                      // row panel 16x132
  double* Scd = (double*)(smraw + 16 * RS * 8);      // 8 wave scratches 16x17
  double* Pv  = (double*)(smraw + 16 * RS * 8 + 8 * 16 * SS * 8); // Pi 16x17

  const int bid = blockIdx.x;
  const int g = bid / NF, f = bid % NF;
  const int tid = threadIdx.x;
  const int wv = tid >> 6, ln = tid & 63;
  const int m  = ln & 15, kq = ln >> 4;
  double* S = Scd + wv * 16 * SS;

  double csum = 0.0;
  for (int q = 0; q < NF; ++q) { double c = (double)C[q]; csum += c * c; }
  double cn = sqrt(csum); if (cn < 1e-12) cn = 1e-12;
  const double a4 = 6.25e-6;                         // (STEP/2)^4
  const double coef = 1.4142135623730951 * a4 * ((double)C[f] / cn);
  const float  bf = (float)((double)f * 0.1);
  const double bb = (double)bf;
  const double c3 = -4.0 * bb;
  const double c2 = 6.0 * bb * bb;
  const double c1 = -4.0 * bb * bb * bb;
  const double c0 = bb * bb * bb * bb + a4;

  int rIdx[4], cIdx[4];
  {
    d4 z = {0.0, 0.0, 0.0, 0.0};
    d4 pr = __builtin_amdgcn_mfma_f64_16x16x4f64((double)m, 1.0, z, 0, 0, 0);
    d4 pc = __builtin_amdgcn_mfma_f64_16x16x4f64(1.0, (double)m, z, 0, 0, 0);
#pragma unroll
    for (int r = 0; r < 4; ++r) {
      rIdx[r] = ((int)(pr[r] * 0.25 + 0.5)) & 15;
      cIdx[r] = ((int)(pc[r] * 0.25 + 0.5)) & 15;
    }
  }

  // phase A: assemble T (D-layout) from the power matrices -- pure n^2
  const float*  Lg  = L  + (size_t)g * NN * NN;
  const double* L2g = L2 + (size_t)g * NN * NN;
  const double* L3g = L3 + (size_t)g * NN * NN;
  const double* L4g = L4 + (size_t)g * NN * NN;
  d4 T[8];
#pragma unroll
  for (int cb = 0; cb < 8; ++cb)
#pragma unroll
    for (int r = 0; r < 4; ++r) {
      int i = 16 * wv + rIdx[r], j = 16 * cb + cIdx[r];
      int idx = i * NN + j;
      double v = L4g[idx];
      v = fma(c3, L3g[idx], v);
      v = fma(c2, L2g[idx], v);
      v = fma(c1, (double)Lg[idx], v);
      if (i == j) v += c0;
      T[cb][r] = v;
    }

  // phase 4: blocked GJ, 8 steps, 3 block-barriers each, NOT unrolled
#pragma unroll 1
  for (int t = 0; t < 8; ++t) {
    if (wv == t) {
#pragma unroll
      for (int cb = 0; cb < 8; ++cb)
#pragma unroll
        for (int r = 0; r < 4; ++r)
          Rp[rIdx[r] * RS + 16 * cb + cIdx[r]] = T[cb][r];
    }
    __syncthreads();                                 // B1 (Rp visible)

    if (wv == t) {
      double sr[4];
#pragma unroll
      for (int r = 0; r < 4; ++r) sr[r] = Rp[(4 * r + kq) * RS + 16 * t + m];
#pragma unroll
      for (int k = 0; k < 16; ++k) {
        const int kr = k >> 2, kl = k & 3;
        double pv   = __shfl(sr[kr], 16 * kl + k);
        double rowv = __shfl(sr[kr], 16 * kl + m);
        double cv[4];
#pragma unroll
        for (int r = 0; r < 4; ++r) cv[r] = __shfl(sr[r], 16 * kq + k);
        double dp = 1.0 / pv;
#pragma unroll
        for (int r = 0; r < 4; ++r) {
          int i = 4 * r + kq;
          double nv;
          if (i == k)      nv = (m == k) ? dp : rowv * dp;
          else if (m == k) nv = -cv[r] * dp;
          else             nv = fma(-(cv[r] * dp), rowv, sr[r]);
          sr[r] = nv;
        }
      }
#pragma unroll
      for (int r = 0; r < 4; ++r) Pv[(4 * r + kq) * SS + m] = sr[r];
    }
    __syncthreads();                                 // B2 (Pi visible)

#pragma unroll
    for (int cb = 0; cb < 8; ++cb) {
      if (cb != t) continue;
      if (wv == t) {
#pragma unroll
        for (int r = 0; r < 4; ++r) T[cb][r] = Pv[rIdx[r] * SS + cIdx[r]];
      } else {
#pragma unroll
        for (int r = 0; r < 4; ++r) S[rIdx[r] * SS + cIdx[r]] = T[cb][r];
        __builtin_amdgcn_wave_barrier();
        d4 ncv = {0.0, 0.0, 0.0, 0.0};
#pragma unroll
        for (int kc = 0; kc < 4; ++kc) {
          double a = S[m * SS + 4 * kc + kq];
          double b = -Pv[(4 * kc + kq) * SS + m];
          ncv = __builtin_amdgcn_mfma_f64_16x16x4f64(a, b, ncv, 0, 0, 0);
        }
        T[cb] = ncv;
        __builtin_amdgcn_wave_barrier();
#pragma unroll
        for (int r = 0; r < 4; ++r) S[rIdx[r] * SS + cIdx[r]] = T[cb][r];
      }
    }
    __builtin_amdgcn_wave_barrier();

    const double* asrc = (wv == t) ? Pv : S;
#pragma unroll
    for (int cb = 0; cb < 8; ++cb) {
      if (cb == t) continue;
      d4 acc;
      if (wv == t) { acc[0] = 0.0; acc[1] = 0.0; acc[2] = 0.0; acc[3] = 0.0; }
      else         { acc = T[cb]; }
#pragma unroll
      for (int kc = 0; kc < 4; ++kc) {
        double a = asrc[m * SS + 4 * kc + kq];
        double b = Rp[(4 * kc + kq) * RS + 16 * cb + m];
        acc = __builtin_amdgcn_mfma_f64_16x16x4f64(a, b, acc, 0, 0, 0);
      }
      T[cb] = acc;
    }
    __syncthreads();                                 // B3 (Rp/Pv reads done)
  }

  // phase 5: W += coef * K^{-1}
  float* Wg = W + (size_t)g * NN * NN;
#pragma unroll
  for (int cb = 0; cb < 8; ++cb)
#pragma unroll
    for (int r = 0; r < 4; ++r)
      atomicAdd(&Wg[(16 * wv + rIdx[r]) * NN + 16 * cb + cIdx[r]],
                (float)(coef * T[cb][r]));
}

// ---------------------------------------------------------------------------
// K3 (R26): k-loop LDS ops vectorized WITHOUT bank conflicts.
// Thread columns remapped to {4tc..4tc+3} U {64+4tc..64+4tc+3}: b128 reads
// at word k*TS+4tc give start-bank 4tc%32 -> only tc/tc+8 alias = 2-way
// (free, m136). R23's 8tc mapping was 4-way read + 16-way write conflict.
// Only the x128 k-loops are vectorized; once-per-block transpose/subtract
// stay scalar (R23 lesson: they don't matter). GEMM1 d-cols and GEMM2
// j-cols are independent mappings; per-output FMA order unchanged =>
// bit-identical results. G stores become float4.
// ---------------------------------------------------------------------------
__global__ __launch_bounds__(512, 4) void k3_fused(
    const float* __restrict__ x, const float* __restrict__ rs,
    const float* __restrict__ W, float* __restrict__ Gp,
    float* __restrict__ emb, int F0, int R, int DTOT, int NCH,
    float rscale) {
  extern __shared__ float sm3[];
  float* ldsX = sm3;                 // 128*132 f32: X, later yT (in place)
  float* embA = sm3 + NN * TS;       // 128 f32 emb accumulator
  const int bid = blockIdx.x;
  const int g = bid / NCH;
  const int c = bid % NCH;
  const int d0 = c * 128;
  const int tid = threadIdx.x, tr = tid >> 4, tc = tid & 15;

  const float* xg = x + (size_t)g * NN * F0;
  const float* rg = rs + (size_t)g * NN * R;
  for (int e = tid; e < NN * NN; e += 512) {
    int k = e >> 7, dl = e & 127;
    int d = d0 + dl;
    float v = 0.f;
    if (d < DTOT) v = (d < F0) ? xg[k * F0 + d] : rg[k * R + (d - F0)] * rscale;
    ldsX[k * TS + dl] = v;
  }
  if (tid < NN) embA[tid] = 0.f;
  __syncthreads();

  // first gemm: y = X - W@X. Thread owns rows 4tr+v, d-cols 4tc+u / 64+4tc+u.
  const float* Wg = W + (size_t)g * NN * NN;
  float acc[4][8];
#pragma unroll
  for (int v = 0; v < 4; ++v)
#pragma unroll
    for (int u = 0; u < 8; ++u) acc[v][u] = 0.f;
  float4 w4 = *(const float4*)(Wg + 4 * tr);
  for (int k = 0; k < NN; ++k) {
    float4 w4n;
    if (k < NN - 1) w4n = *(const float4*)(Wg + (k + 1) * NN + 4 * tr);
    float4 xa = *(const float4*)(ldsX + k * TS + 4 * tc);        // 2-way, free
    float4 xb = *(const float4*)(ldsX + k * TS + 64 + 4 * tc);   // 2-way, free
    float xv[8] = {xa.x, xa.y, xa.z, xa.w, xb.x, xb.y, xb.z, xb.w};
    float wvv[4] = {w4.x, w4.y, w4.z, w4.w};
#pragma unroll
    for (int v = 0; v < 4; ++v)
#pragma unroll
      for (int u = 0; u < 8; ++u) acc[v][u] = fmaf(wvv[v], xv[u], acc[v][u]);
    w4 = w4n;
  }
  // y = X - (W@X)
#pragma unroll
  for (int v = 0; v < 4; ++v) {
    float4 sa = *(const float4*)(ldsX + (4 * tr + v) * TS + 4 * tc);
    float4 sb = *(const float4*)(ldsX + (4 * tr + v) * TS + 64 + 4 * tc);
    acc[v][0] = sa.x - acc[v][0]; acc[v][1] = sa.y - acc[v][1];
    acc[v][2] = sa.z - acc[v][2]; acc[v][3] = sa.w - acc[v][3];
    acc[v][4] = sb.x - acc[v][4]; acc[v][5] = sb.y - acc[v][5];
    acc[v][6] = sb.z - acc[v][6]; acc[v][7] = sb.w - acc[v][7];
  }

  // emb partials: column sums of y via LDS atomics (once per block)
#pragma unroll
  for (int u = 0; u < 8; ++u) {
    int cu = (u < 4) ? (4 * tc + u) : (64 + 4 * tc + (u - 4));
    float s = acc[0][u] + acc[1][u] + acc[2][u] + acc[3][u];
    atomicAdd(&embA[cu], s);
  }
  __syncthreads();                 // all X reads + embA adds complete

  // write yT in place over the dead X buffer (scalar, once per block)
#pragma unroll
  for (int v = 0; v < 4; ++v)
#pragma unroll
    for (int u = 0; u < 8; ++u) {
      int cu = (u < 4) ? (4 * tc + u) : (64 + 4 * tc + (u - 4));
      ldsX[cu * TS + 4 * tr + v] = acc[v][u];
    }
  __syncthreads();

  // emb write (fire-and-forget, overlaps second gemm)
  if (tid < 128) {
    int d = d0 + tid;
    if (d < DTOT) emb[(size_t)g * 1152 + d] = embA[tid] * (1.f / 128.f);
  }

  // second gemm: G[i][j] = sum_d y[i,d]*y[j,d]; thread j-cols 4tc+u/64+4tc+u
  float gg[4][8];
#pragma unroll
  for (int v = 0; v < 4; ++v)
#pragma unroll
    for (int u = 0; u < 8; ++u) gg[v][u] = 0.f;
  for (int dl = 0; dl < NN; ++dl) {
    float4 a4v = *(const float4*)(ldsX + dl * TS + 4 * tr);      // broadcast
    float4 ba  = *(const float4*)(ldsX + dl * TS + 4 * tc);      // 2-way, free
    float4 bb  = *(const float4*)(ldsX + dl * TS + 64 + 4 * tc); // 2-way, free
    float bv[8] = {ba.x, ba.y, ba.z, ba.w, bb.x, bb.y, bb.z, bb.w};
    float av[4] = {a4v.x, a4v.y, a4v.z, a4v.w};
#pragma unroll
    for (int v = 0; v < 4; ++v)
#pragma unroll
      for (int u = 0; u < 8; ++u) gg[v][u] = fmaf(av[v], bv[u], gg[v][u]);
  }
  float* Gc = Gp + ((size_t)c * 64 + g) * NN * NN;
#pragma unroll
  for (int v = 0; v < 4; ++v) {
    float4 lo = {gg[v][0], gg[v][1], gg[v][2], gg[v][3]};
    float4 hi = {gg[v][4], gg[v][5], gg[v][6], gg[v][7]};
    *(float4*)(Gc + (4 * tr + v) * NN + 4 * tc) = lo;
    *(float4*)(Gc + (4 * tr + v) * NN + 64 + 4 * tc) = hi;
  }
}

// ---------------------------------------------------------------------------
// KGRED (R25): dense G = sum_c Gp[c] on a FULL grid (1024 blocks, float4
// per thread).
// ---------------------------------------------------------------------------
__global__ __launch_bounds__(256) void kgred(
    const float* __restrict__ Gp, float* __restrict__ G, int NCH) {
  const size_t cstride = (size_t)64 * NN * NN;
  size_t idx = ((size_t)blockIdx.x * 256 + threadIdx.x) * 4;
  float4 s = *(const float4*)(Gp + idx);
  for (int c = 1; c < NCH; ++c) {
    float4 v = *(const float4*)(Gp + c * cstride + idx);
    s.x += v.x; s.y += v.y; s.z += v.z; s.w += v.w;
  }
  *(float4*)(G + idx) = s;
}

// ---------------------------------------------------------------------------
// K45 (R22 form): blocks 0..63 = k4 (sp terms from dense G); 64..127 = k5a.
// ---------------------------------------------------------------------------
__global__ __launch_bounds__(256) void k45_fused(
    const float* __restrict__ G, double* __restrict__ spt,
    const float* __restrict__ emb, float* __restrict__ Dm, int DTOT) {
  __shared__ float inr[NN];
  __shared__ double red[4];
  const int bid = blockIdx.x, tid = threadIdx.x;
  if (bid < 64) {
    const int g = bid;
    const float* Gg = G + (size_t)g * NN * NN;
    if (tid < NN) {
      float n = sqrtf(fmaxf(Gg[tid * NN + tid], 0.f));
      inr[tid] = 1.f / fmaxf(n, 1e-12f);
    }
    __syncthreads();
    double s = 0.0;
    for (int e = tid; e < NN * NN; e += 256) {
      int i = e >> 7, j = e & 127;
      s += (double)(fabsf(Gg[e]) * inr[i] * inr[j]);
    }
    for (int off = 32; off; off >>= 1) s += __shfl_down(s, off);
    int wave = tid >> 6, lane = tid & 63;
    if (lane == 0) red[wave] = s;
    __syncthreads();
    if (tid == 0) spt[g] = -(red[0] + red[1] + red[2] + red[3]) / (double)(NN * NN);
  } else {
    const int i = bid - 64;
    const int wv = tid >> 6, l = tid & 63;
    float ei[18];
#pragma unroll
    for (int s = 0; s < 18; ++s) {
      int d = l + 64 * s;
      ei[s] = (d < DTOT) ? emb[(size_t)i * 1152 + d] : 0.f;
    }
    for (int jj = 0; jj < 16; ++jj) {
      int j = 4 * jj + wv;
      float acc = 0.f;
#pragma unroll
      for (int s = 0; s < 18; ++s) {
        int d = l + 64 * s;
        if (d < DTOT) {
          float df = ei[s] - emb[(size_t)j * 1152 + d];
          acc = fmaf(df, df, acc);
        }
      }
      for (int off = 32; off; off >>= 1) acc += __shfl_down(acc, off);
      if (l == 0) Dm[i * 64 + j] = (acc > 0.f) ? sqrtf(acc) : 0.f;
    }
  }
}

// ---------------------------------------------------------------------------
// K5b (R23): 4 waves, one class per wave; spt reduce on wave 0.
// ---------------------------------------------------------------------------
__global__ __launch_bounds__(256) void k5b_final(
    const float* __restrict__ Dm, const double* __restrict__ spt,
    const float* __restrict__ C, int NF,
    const int* __restrict__ ncls, float* __restrict__ out) {
  __shared__ double redH[8];     // per-wave {hl1, hl2}
  __shared__ double redS;
  const int tid = threadIdx.x;
  const int wv = tid >> 6, lane = tid & 63;
  const int nc = ncls[0];

  double hl1 = 0.0, hl2 = 0.0;
  const double beta = 1.0 / (double)nc + 1e-13;
  for (int cc = wv; cc < nc; cc += 4) {
    bool ip = (lane % nc) == cc;
    double ps = 0.0, ns = 0.0;
    for (int j = 0; j < 64; ++j) {
      double dv = (double)Dm[lane * 64 + j];
      bool jp = (j % nc) == cc;
      if (ip && jp) ps += dv;
      if (!ip && !jp) ns += dv;
    }
    for (int off = 32; off; off >>= 1) {
      ps += __shfl_down(ps, off);
      ns += __shfl_down(ns, off);
    }
    if (lane == 0) {
      int npos = 0;
      for (int q = 0; q < 64; ++q) if (q % nc == cc) npos++;
      int nneg = 64 - npos;
      hl2 += ps / ((double)npos * (double)npos);
      hl1 += -(ns / ((double)nneg * (double)nneg)) / beta;
    }
  }
  if (lane == 0) { redH[2 * wv] = hl1; redH[2 * wv + 1] = hl2; }

  if (wv == 0) {
    double spf = spt[lane] * exp(-((double)(64 - lane)) * log(64.0));
    for (int off = 32; off; off >>= 1) spf += __shfl_down(spf, off);
    if (lane == 0) redS = spf;
  }
  __syncthreads();

  if (tid == 0) {
    double h1 = redH[0] + redH[2] + redH[4] + redH[6];
    double h2 = redH[1] + redH[3] + redH[5] + redH[7];
    double l1 = 0.0, l2 = 0.0;
    for (int q = 0; q < NF; ++q) { double cv = (double)C[q]; l1 += fabs(cv); l2 += cv * cv; }
    l2 = sqrt(l2); if (l2 < 1e-12) l2 = 1e-12;
    double dims = sqrt((double)NF);
    double sc = (dims - l1 / l2) / (dims - 1.0);
    out[0] = (float)(sc + h2 + h1 + redS);
  }
}

// ---------------------------------------------------------------------------
extern "C" void kernel_launch(void* const* d_in, const int* in_sizes, int n_in,
                              void* d_out, int out_size, void* d_ws, size_t ws_size,
                              hipStream_t stream) {
  (void)n_in; (void)out_size; (void)ws_size;
  const float* x    = (const float*)d_in[0];
  const float* rs   = (const float*)d_in[1];
  const float* C    = (const float*)d_in[2];
  const int*   esrc = (const int*)d_in[3];
  const int*   edst = (const int*)d_in[4];
  const int*   ncls = (const int*)d_in[5];
  float* out = (float*)d_out;

  const int F0   = in_sizes[0] / (64 * 128);
  const int R    = in_sizes[1] / (64 * 128);
  const int NF   = in_sizes[2];
  const int E    = in_sizes[3] / 64;
  const int DTOT = F0 + R;
  const int NCH  = (DTOT + 127) / 128;
  const float rscale = (float)(1.0 / sqrt((double)R));

  char* ws = (char*)d_ws;
  size_t off = 0;
  float*  L    = (float*)(ws + off);  off += (size_t)64 * NN * NN * 4;   // 4MB; reused as dense G after k2
  float*  W    = (float*)(ws + off);  off += (size_t)64 * NN * NN * 4;   // 4MB
  // Gp overlays the L2d/L3d/L4d region (dead after k2) + extension:
  // NCH x 64 x 128 x 128 f32, c-major.
  float*  Gp   = (float*)(ws + off);
  double* L2d  = (double*)(ws + off); off += (size_t)64 * NN * NN * 8;   // 8MB
  double* L3d  = (double*)(ws + off); off += (size_t)64 * NN * NN * 8;   // 8MB
  double* L4d  = (double*)(ws + off); off += (size_t)64 * NN * NN * 8;   // 8MB
  {
    size_t gp_bytes = (size_t)NCH * 64 * NN * NN * 4;
    size_t have = (size_t)3 * 64 * NN * NN * 8;
    if (gp_bytes > have) off += gp_bytes - have;
  }
  float*  emb  = (float*)(ws + off);  off += (size_t)64 * 1152 * 4;
  double* spt  = (double*)(ws + off); off += (size_t)64 * 8;
  float*  Dm   = (float*)(ws + off);  off += (size_t)64 * 64 * 4;
  float*  G    = L;                   // dense G reuses L (dead after k2)

  hipMemsetAsync(W, 0, (size_t)64 * NN * NN * 4, stream);

  const int lds1 = (NN * SM + NN) * 4;             // 66560
  const int ldsf = NN * SF * 4;                    // 67584 (f32 staging)
  const int lds2 = 16 * RS * 8 + 8 * 16 * SS * 8 + 16 * SS * 8;  // 36480
  const int lds3 = (NN * TS + NN) * 4;             // 68096 -> 2 blocks/CU
  hipFuncSetAttribute((const void*)k1_lap,    hipFuncAttributeMaxDynamicSharedMemorySize, lds1);
  hipFuncSetAttribute((const void*)kpow2,     hipFuncAttributeMaxDynamicSharedMemorySize, ldsf);
  hipFuncSetAttribute((const void*)kpow34,    hipFuncAttributeMaxDynamicSharedMemorySize, ldsf);
  hipFuncSetAttribute((const void*)k2_filter, hipFuncAttributeMaxDynamicSharedMemorySize, lds2);
  hipFuncSetAttribute((const void*)k3_fused,  hipFuncAttributeMaxDynamicSharedMemorySize, lds3);

  k1_lap<<<64, 256, lds1, stream>>>(esrc, edst, E, L);
  kpow2<<<512, 512, ldsf, stream>>>(L, L2d);
  kpow34<<<512, 512, ldsf, stream>>>(L, L2d, L3d, L4d);
  k2_filter<<<64 * NF, 512, lds2, stream>>>(L, L2d, L3d, L4d, C, NF, W);
  k3_fused<<<64 * NCH, 512, lds3, stream>>>(x, rs, W, Gp, emb, F0, R, DTOT, NCH, rscale);
  kgred<<<1024, 256, 0, stream>>>(Gp, G, NCH);
  k45_fused<<<128, 256, 0, stream>>>(G, spt, emb, Dm, DTOT);
  k5b_final<<<1, 256, 0, stream>>>(Dm, spt, C, NF, ncls, out);
}

// Round 10
// 579.609 us; speedup vs baseline: 1.3454x; 1.0057x over previous
//
#include <hip/hip_runtime.h>
#include <math.h>

#define NN 128
#define SM 129   // padded LDS stride for 128-wide f32 tiles
#define TS 132   // k3-128 tile stride
#define RS 132   // row-panel stride (doubles)
#define SS 17    // per-wave scratch stride (doubles)
#define SF 132   // f32 staging stride (16B-aligned rows -> float4)
#define XS 68    // k3-64 X stride (128x68 f32 = 34.8KB)
#define YS 132   // k3-64 yT stride (64x132 f32 = 33.8KB, overlays X)

typedef double d4 __attribute__((ext_vector_type(4)));

// ---------------------------------------------------------------------------
// K1 (R17): build symmetric-normalized Laplacian per graph (f32) only.
// ---------------------------------------------------------------------------
__global__ __launch_bounds__(256) void k1_lap(
    const int* __restrict__ src, const int* __restrict__ dst,
    int E, float* __restrict__ Lout) {
  extern __shared__ float sm1[];            // A[128*129] + dinv[128]
  float* A    = sm1;
  float* dinv = sm1 + NN * SM;
  const int g   = blockIdx.x;
  const int tid = threadIdx.x;

  for (int e = tid; e < NN * NN; e += 256) {
    int i = e >> 7, j = e & 127;
    A[i * SM + j] = 0.f;
  }
  __syncthreads();
  const int* s = src + (size_t)g * E;
  const int* d = dst + (size_t)g * E;
  for (int e = tid; e < E; e += 256) {
    int a = s[e], b = d[e];
    A[a * SM + b] = 1.f;     // benign races: all write 1.0
    A[b * SM + a] = 1.f;
  }
  __syncthreads();
  if (tid < NN) {
    float acc = 0.f;
    for (int j = 0; j < NN; ++j) acc += A[tid * SM + j];
    dinv[tid] = (acc > 0.f) ? (float)(1.0 / sqrt((double)acc)) : 0.f;
  }
  __syncthreads();
  float* Lg = Lout + (size_t)g * NN * NN;
  for (int e = tid; e < NN * NN; e += 256) {
    int i = e >> 7, j = e & 127;
    Lg[e] = ((i == j) ? 1.f : 0.f) - dinv[i] * dinv[j] * A[i * SM + j];
  }
}

// ---------------------------------------------------------------------------
// KPOW2 (R22): L2 = L @ L. 512 blocks. L staged f32 in LDS. 2 blocks/CU.
// ---------------------------------------------------------------------------
__global__ __launch_bounds__(512, 4) void kpow2(
    const float* __restrict__ L, double* __restrict__ L2) {
  extern __shared__ float Bs[];             // 128 x 132 f32
  const int bid = blockIdx.x;
  const int g = bid >> 3, q = bid & 7;
  const int tid = threadIdx.x;
  const int wv = tid >> 6, ln = tid & 63;
  const int m  = ln & 15, kq = ln >> 4;
  const int rb = 16 * q;                    // row-band base
  const int cb = wv;                        // column tile

  int rIdx[4], cIdx[4];
  {
    d4 z = {0.0, 0.0, 0.0, 0.0};
    d4 pr = __builtin_amdgcn_mfma_f64_16x16x4f64((double)m, 1.0, z, 0, 0, 0);
    d4 pc = __builtin_amdgcn_mfma_f64_16x16x4f64(1.0, (double)m, z, 0, 0, 0);
#pragma unroll
    for (int r = 0; r < 4; ++r) {
      rIdx[r] = ((int)(pr[r] * 0.25 + 0.5)) & 15;
      cIdx[r] = ((int)(pc[r] * 0.25 + 0.5)) & 15;
    }
  }

  const float* Lg = L + (size_t)g * NN * NN;
  for (int e4 = tid; e4 < (NN * NN) / 4; e4 += 512) {
    int i = e4 >> 5, j4 = (e4 & 31) * 4;
    *(float4*)(Bs + i * SF + j4) = *(const float4*)(Lg + i * NN + j4);
  }
  __syncthreads();

  d4 acc = {0.0, 0.0, 0.0, 0.0};
  for (int kc = 0; kc < 32; ++kc) {
    double a = (double)Bs[(rb + m) * SF + 4 * kc + kq];
    double b = (double)Bs[(4 * kc + kq) * SF + 16 * cb + m];
    acc = __builtin_amdgcn_mfma_f64_16x16x4f64(a, b, acc, 0, 0, 0);
  }
  double* out = L2 + (size_t)g * NN * NN;
#pragma unroll
  for (int r = 0; r < 4; ++r)
    out[(rb + rIdx[r]) * NN + 16 * cb + cIdx[r]] = acc[r];
}

// ---------------------------------------------------------------------------
// KPOW34 (R22): 512 blocks = g(6b) x quarter(2b) x job(1b).
// ---------------------------------------------------------------------------
__global__ __launch_bounds__(512, 4) void kpow34(
    const float* __restrict__ L, const double* __restrict__ L2,
    double* __restrict__ L3, double* __restrict__ L4) {
  extern __shared__ float Bs[];             // 128 x 132 f32 (job0 only)
  const int bid = blockIdx.x;
  const int g = bid >> 3, q = (bid >> 1) & 3, job = bid & 1;
  const int tid = threadIdx.x;
  const int wv = tid >> 6, ln = tid & 63;
  const int m  = ln & 15, kq = ln >> 4;
  const int rb = 32 * q + 16 * (wv & 1);
  const int cb0 = 2 * (wv >> 1);

  int rIdx[4], cIdx[4];
  {
    d4 z = {0.0, 0.0, 0.0, 0.0};
    d4 pr = __builtin_amdgcn_mfma_f64_16x16x4f64((double)m, 1.0, z, 0, 0, 0);
    d4 pc = __builtin_amdgcn_mfma_f64_16x16x4f64(1.0, (double)m, z, 0, 0, 0);
#pragma unroll
    for (int r = 0; r < 4; ++r) {
      rIdx[r] = ((int)(pr[r] * 0.25 + 0.5)) & 15;
      cIdx[r] = ((int)(pc[r] * 0.25 + 0.5)) & 15;
    }
  }

  const float*  Lg  = L  + (size_t)g * NN * NN;
  const double* L2g = L2 + (size_t)g * NN * NN;
  if (job == 0) {
    for (int e4 = tid; e4 < (NN * NN) / 4; e4 += 512) {
      int i = e4 >> 5, j4 = (e4 & 31) * 4;
      *(float4*)(Bs + i * SF + j4) = *(const float4*)(Lg + i * NN + j4);
    }
  }
  __syncthreads();

  d4 acc[2];
#pragma unroll
  for (int c = 0; c < 2; ++c) {
    acc[c][0] = 0.0; acc[c][1] = 0.0; acc[c][2] = 0.0; acc[c][3] = 0.0;
  }
  if (job == 0) {
    for (int kc = 0; kc < 32; ++kc) {
      double a = L2g[(rb + m) * NN + 4 * kc + kq];
#pragma unroll
      for (int c = 0; c < 2; ++c) {
        double b = (double)Bs[(4 * kc + kq) * SF + 16 * (cb0 + c) + m];
        acc[c] = __builtin_amdgcn_mfma_f64_16x16x4f64(a, b, acc[c], 0, 0, 0);
      }
    }
  } else {
    for (int kc = 0; kc < 32; ++kc) {
      double a = L2g[(rb + m) * NN + 4 * kc + kq];
#pragma unroll
      for (int c = 0; c < 2; ++c) {
        double b = L2g[(4 * kc + kq) * NN + 16 * (cb0 + c) + m];
        acc[c] = __builtin_amdgcn_mfma_f64_16x16x4f64(a, b, acc[c], 0, 0, 0);
      }
    }
  }
  double* out = (job == 0 ? L3 : L4) + (size_t)g * NN * NN;
#pragma unroll
  for (int c = 0; c < 2; ++c)
#pragma unroll
    for (int r = 0; r < 4; ++r)
      out[(rb + rIdx[r]) * NN + 16 * (cb0 + c) + cIdx[r]] = acc[c][r];
}

// ---------------------------------------------------------------------------
// K2 (R14 exact, FROZEN): algebraic assembly + blocked GJ with serial-Pi.
// 268us stable; VGPR 64 + 64 AGPR = full 128 budget at (512,4).
// R18/R19/R21 restructurings ALL spilled to scratch. DO NOT MODIFY.
// ---------------------------------------------------------------------------
__global__ __launch_bounds__(512, 4) void k2_filter(
    const float* __restrict__ L, const double* __restrict__ L2,
    const double* __restrict__ L3, const double* __restrict__ L4,
    const float* __restrict__ C, int NF, float* __restrict__ W) {
  extern __shared__ char smraw[];
  double* Rp  = (double*)smraw;                      // row panel 16x132
  double* Scd = (double*)(smraw + 16 * RS * 8);      // 8 wave scratches 16x17
  double* Pv  = (double*)(smraw + 16 * RS * 8 + 8 * 16 * SS * 8); // Pi 16x17

  const int bid = blockIdx.x;
  const int g = bid / NF, f = bid % NF;
  const int tid = threadIdx.x;
  const int wv = tid >> 6, ln = tid & 63;
  const int m  = ln & 15, kq = ln >> 4;
  double* S = Scd + wv * 16 * SS;

  double csum = 0.0;
  for (int q = 0; q < NF; ++q) { double c = (double)C[q]; csum += c * c; }
  double cn = sqrt(csum); if (cn < 1e-12) cn = 1e-12;
  const double a4 = 6.25e-6;                         // (STEP/2)^4
  const double coef = 1.4142135623730951 * a4 * ((double)C[f] / cn);
  const float  bf = (float)((double)f * 0.1);
  const double bb = (double)bf;
  const double c3 = -4.0 * bb;
  const double c2 = 6.0 * bb * bb;
  const double c1 = -4.0 * bb * bb * bb;
  const double c0 = bb * bb * bb * bb + a4;

  int rIdx[4], cIdx[4];
  {
    d4 z = {0.0, 0.0, 0.0, 0.0};
    d4 pr = __builtin_amdgcn_mfma_f64_16x16x4f64((double)m, 1.0, z, 0, 0, 0);
    d4 pc = __builtin_amdgcn_mfma_f64_16x16x4f64(1.0, (double)m, z, 0, 0, 0);
#pragma unroll
    for (int r = 0; r < 4; ++r) {
      rIdx[r] = ((int)(pr[r] * 0.25 + 0.5)) & 15;
      cIdx[r] = ((int)(pc[r] * 0.25 + 0.5)) & 15;
    }
  }

  // phase A: assemble T (D-layout) from the power matrices -- pure n^2
  const float*  Lg  = L  + (size_t)g * NN * NN;
  const double* L2g = L2 + (size_t)g * NN * NN;
  const double* L3g = L3 + (size_t)g * NN * NN;
  const double* L4g = L4 + (size_t)g * NN * NN;
  d4 T[8];
#pragma unroll
  for (int cb = 0; cb < 8; ++cb)
#pragma unroll
    for (int r = 0; r < 4; ++r) {
      int i = 16 * wv + rIdx[r], j = 16 * cb + cIdx[r];
      int idx = i * NN + j;
      double v = L4g[idx];
      v = fma(c3, L3g[idx], v);
      v = fma(c2, L2g[idx], v);
      v = fma(c1, (double)Lg[idx], v);
      if (i == j) v += c0;
      T[cb][r] = v;
    }

  // phase 4: blocked GJ, 8 steps, 3 block-barriers each, NOT unrolled
#pragma unroll 1
  for (int t = 0; t < 8; ++t) {
    if (wv == t) {
#pragma unroll
      for (int cb = 0; cb < 8; ++cb)
#pragma unroll
        for (int r = 0; r < 4; ++r)
          Rp[rIdx[r] * RS + 16 * cb + cIdx[r]] = T[cb][r];
    }
    __syncthreads();                                 // B1 (Rp visible)

    if (wv == t) {
      double sr[4];
#pragma unroll
      for (int r = 0; r < 4; ++r) sr[r] = Rp[(4 * r + kq) * RS + 16 * t + m];
#pragma unroll
      for (int k = 0; k < 16; ++k) {
        const int kr = k >> 2, kl = k & 3;
        double pv   = __shfl(sr[kr], 16 * kl + k);
        double rowv = __shfl(sr[kr], 16 * kl + m);
        double cv[4];
#pragma unroll
        for (int r = 0; r < 4; ++r) cv[r] = __shfl(sr[r], 16 * kq + k);
        double dp = 1.0 / pv;
#pragma unroll
        for (int r = 0; r < 4; ++r) {
          int i = 4 * r + kq;
          double nv;
          if (i == k)      nv = (m == k) ? dp : rowv * dp;
          else if (m == k) nv = -cv[r] * dp;
          else             nv = fma(-(cv[r] * dp), rowv, sr[r]);
          sr[r] = nv;
        }
      }
#pragma unroll
      for (int r = 0; r < 4; ++r) Pv[(4 * r + kq) * SS + m] = sr[r];
    }
    __syncthreads();                                 // B2 (Pi visible)

#pragma unroll
    for (int cb = 0; cb < 8; ++cb) {
      if (cb != t) continue;
      if (wv == t) {
#pragma unroll
        for (int r = 0; r < 4; ++r) T[cb][r] = Pv[rIdx[r] * SS + cIdx[r]];
      } else {
#pragma unroll
        for (int r = 0; r < 4; ++r) S[rIdx[r] * SS + cIdx[r]] = T[cb][r];
        __builtin_amdgcn_wave_barrier();
        d4 ncv = {0.0, 0.0, 0.0, 0.0};
#pragma unroll
        for (int kc = 0; kc < 4; ++kc) {
          double a = S[m * SS + 4 * kc + kq];
          double b = -Pv[(4 * kc + kq) * SS + m];
          ncv = __builtin_amdgcn_mfma_f64_16x16x4f64(a, b, ncv, 0, 0, 0);
        }
        T[cb] = ncv;
        __builtin_amdgcn_wave_barrier();
#pragma unroll
        for (int r = 0; r < 4; ++r) S[rIdx[r] * SS + cIdx[r]] = T[cb][r];
      }
    }
    __builtin_amdgcn_wave_barrier();

    const double* asrc = (wv == t) ? Pv : S;
#pragma unroll
    for (int cb = 0; cb < 8; ++cb) {
      if (cb == t) continue;
      d4 acc;
      if (wv == t) { acc[0] = 0.0; acc[1] = 0.0; acc[2] = 0.0; acc[3] = 0.0; }
      else         { acc = T[cb]; }
#pragma unroll
      for (int kc = 0; kc < 4; ++kc) {
        double a = asrc[m * SS + 4 * kc + kq];
        double b = Rp[(4 * kc + kq) * RS + 16 * cb + m];
        acc = __builtin_amdgcn_mfma_f64_16x16x4f64(a, b, acc, 0, 0, 0);
      }
      T[cb] = acc;
    }
    __syncthreads();                                 // B3 (Rp/Pv reads done)
  }

  // phase 5: W += coef * K^{-1}
  float* Wg = W + (size_t)g * NN * NN;
#pragma unroll
  for (int cb = 0; cb < 8; ++cb)
#pragma unroll
    for (int r = 0; r < 4; ++r)
      atomicAdd(&Wg[(16 * wv + rIdx[r]) * NN + 16 * cb + cIdx[r]],
                (float)(coef * T[cb][r]));
}

// ---------------------------------------------------------------------------
// K3-64 (R27): 64-col chunks -> LDS 35KB -> 4 blocks/CU (32 waves, max occ).
// R26 showed k3 is latency/occupancy-bound (VALUBusy ~8%), not LDS-issue-
// bound; doubling resident waves attacks that. X [128][68] overlaid by yT
// [64][132] in place. k-loop b128 reads stay 2-way-free (stride 68: lanes
// tc/tc+8 alias only). acc[4][4] keeps peak regs ~52 < the 64-VGPR cap of
// __launch_bounds__(512,8). Gp has NCH2=18 partials (72MB, ws-guarded).
// ---------------------------------------------------------------------------
__global__ __launch_bounds__(512, 8) void k3_fused64(
    const float* __restrict__ x, const float* __restrict__ rs,
    const float* __restrict__ W, float* __restrict__ Gp,
    float* __restrict__ emb, int F0, int R, int DTOT, int NCH2,
    float rscale) {
  extern __shared__ float sm3[];
  float* ldsX = sm3;                 // [128][68] X, then [64][132] yT in place
  float* embA = sm3 + 128 * XS;      // 64 f32 emb accumulator
  const int bid = blockIdx.x;
  const int g = bid / NCH2;
  const int c = bid % NCH2;
  const int d0 = c * 64;
  const int tid = threadIdx.x, tr = tid >> 4, tc = tid & 15;

  const float* xg = x + (size_t)g * NN * F0;
  const float* rg = rs + (size_t)g * NN * R;
  for (int e = tid; e < NN * 64; e += 512) {
    int k = e >> 6, dl = e & 63;
    int d = d0 + dl;
    float v = 0.f;
    if (d < DTOT) v = (d < F0) ? xg[k * F0 + d] : rg[k * R + (d - F0)] * rscale;
    ldsX[k * XS + dl] = v;
  }
  if (tid < 64) embA[tid] = 0.f;
  __syncthreads();

  // GEMM1: y = X - W@X. Thread: rows 4tr+v, cols 4tc+u (within chunk).
  const float* Wg = W + (size_t)g * NN * NN;
  float acc[4][4];
#pragma unroll
  for (int v = 0; v < 4; ++v)
#pragma unroll
    for (int u = 0; u < 4; ++u) acc[v][u] = 0.f;
  float4 w4 = *(const float4*)(Wg + 4 * tr);
  for (int k = 0; k < NN; ++k) {
    float4 w4n;
    if (k < NN - 1) w4n = *(const float4*)(Wg + (k + 1) * NN + 4 * tr);
    float4 xa = *(const float4*)(ldsX + k * XS + 4 * tc);  // 2-way, free
    float xv[4] = {xa.x, xa.y, xa.z, xa.w};
    float wvv[4] = {w4.x, w4.y, w4.z, w4.w};
#pragma unroll
    for (int v = 0; v < 4; ++v)
#pragma unroll
      for (int u = 0; u < 4; ++u) acc[v][u] = fmaf(wvv[v], xv[u], acc[v][u]);
    w4 = w4n;
  }
  // y = X - (W@X)
#pragma unroll
  for (int v = 0; v < 4; ++v) {
    float4 sa = *(const float4*)(ldsX + (4 * tr + v) * XS + 4 * tc);
    acc[v][0] = sa.x - acc[v][0]; acc[v][1] = sa.y - acc[v][1];
    acc[v][2] = sa.z - acc[v][2]; acc[v][3] = sa.w - acc[v][3];
  }

  // emb partials: column sums via LDS atomics
#pragma unroll
  for (int u = 0; u < 4; ++u) {
    float s = acc[0][u] + acc[1][u] + acc[2][u] + acc[3][u];
    atomicAdd(&embA[4 * tc + u], s);
  }
  __syncthreads();                 // all X reads + embA adds complete

  // yT [64][132] in place over the dead X buffer (once per block)
#pragma unroll
  for (int v = 0; v < 4; ++v)
#pragma unroll
    for (int u = 0; u < 4; ++u)
      ldsX[(4 * tc + u) * YS + 4 * tr + v] = acc[v][u];
  __syncthreads();

  if (tid < 64) {
    int d = d0 + tid;
    if (d < DTOT) emb[(size_t)g * 1152 + d] = embA[tid] * (1.f / 128.f);
  }

  // GEMM2: G[i][j] += sum_{d in chunk} y[i,d]*y[j,d]; depth 64.
  float gg[4][8];
#pragma unroll
  for (int v = 0; v < 4; ++v)
#pragma unroll
    for (int u = 0; u < 8; ++u) gg[v][u] = 0.f;
  for (int dl = 0; dl < 64; ++dl) {
    float4 a4v = *(const float4*)(ldsX + dl * YS + 4 * tr);      // broadcast
    float4 ba  = *(const float4*)(ldsX + dl * YS + 4 * tc);      // 2-way
    float4 bb  = *(const float4*)(ldsX + dl * YS + 64 + 4 * tc); // 2-way
    float bv[8] = {ba.x, ba.y, ba.z, ba.w, bb.x, bb.y, bb.z, bb.w};
    float av[4] = {a4v.x, a4v.y, a4v.z, a4v.w};
#pragma unroll
    for (int v = 0; v < 4; ++v)
#pragma unroll
      for (int u = 0; u < 8; ++u) gg[v][u] = fmaf(av[v], bv[u], gg[v][u]);
  }
  float* Gc = Gp + ((size_t)c * 64 + g) * NN * NN;
#pragma unroll
  for (int v = 0; v < 4; ++v) {
    float4 lo = {gg[v][0], gg[v][1], gg[v][2], gg[v][3]};
    float4 hi = {gg[v][4], gg[v][5], gg[v][6], gg[v][7]};
    *(float4*)(Gc + (4 * tr + v) * NN + 4 * tc) = lo;
    *(float4*)(Gc + (4 * tr + v) * NN + 64 + 4 * tc) = hi;
  }
}

// ---------------------------------------------------------------------------
// K3-128 (R26, fallback if workspace too small for 18 Gp partials).
// ---------------------------------------------------------------------------
__global__ __launch_bounds__(512, 4) void k3_fused(
    const float* __restrict__ x, const float* __restrict__ rs,
    const float* __restrict__ W, float* __restrict__ Gp,
    float* __restrict__ emb, int F0, int R, int DTOT, int NCH,
    float rscale) {
  extern __shared__ float sm3[];
  float* ldsX = sm3;                 // 128*132 f32: X, later yT (in place)
  float* embA = sm3 + NN * TS;       // 128 f32 emb accumulator
  const int bid = blockIdx.x;
  const int g = bid / NCH;
  const int c = bid % NCH;
  const int d0 = c * 128;
  const int tid = threadIdx.x, tr = tid >> 4, tc = tid & 15;

  const float* xg = x + (size_t)g * NN * F0;
  const float* rg = rs + (size_t)g * NN * R;
  for (int e = tid; e < NN * NN; e += 512) {
    int k = e >> 7, dl = e & 127;
    int d = d0 + dl;
    float v = 0.f;
    if (d < DTOT) v = (d < F0) ? xg[k * F0 + d] : rg[k * R + (d - F0)] * rscale;
    ldsX[k * TS + dl] = v;
  }
  if (tid < NN) embA[tid] = 0.f;
  __syncthreads();

  const float* Wg = W + (size_t)g * NN * NN;
  float acc[4][8];
#pragma unroll
  for (int v = 0; v < 4; ++v)
#pragma unroll
    for (int u = 0; u < 8; ++u) acc[v][u] = 0.f;
  float4 w4 = *(const float4*)(Wg + 4 * tr);
  for (int k = 0; k < NN; ++k) {
    float4 w4n;
    if (k < NN - 1) w4n = *(const float4*)(Wg + (k + 1) * NN + 4 * tr);
    float4 xa = *(const float4*)(ldsX + k * TS + 4 * tc);
    float4 xb = *(const float4*)(ldsX + k * TS + 64 + 4 * tc);
    float xv[8] = {xa.x, xa.y, xa.z, xa.w, xb.x, xb.y, xb.z, xb.w};
    float wvv[4] = {w4.x, w4.y, w4.z, w4.w};
#pragma unroll
    for (int v = 0; v < 4; ++v)
#pragma unroll
      for (int u = 0; u < 8; ++u) acc[v][u] = fmaf(wvv[v], xv[u], acc[v][u]);
    w4 = w4n;
  }
#pragma unroll
  for (int v = 0; v < 4; ++v) {
    float4 sa = *(const float4*)(ldsX + (4 * tr + v) * TS + 4 * tc);
    float4 sb = *(const float4*)(ldsX + (4 * tr + v) * TS + 64 + 4 * tc);
    acc[v][0] = sa.x - acc[v][0]; acc[v][1] = sa.y - acc[v][1];
    acc[v][2] = sa.z - acc[v][2]; acc[v][3] = sa.w - acc[v][3];
    acc[v][4] = sb.x - acc[v][4]; acc[v][5] = sb.y - acc[v][5];
    acc[v][6] = sb.z - acc[v][6]; acc[v][7] = sb.w - acc[v][7];
  }

#pragma unroll
  for (int u = 0; u < 8; ++u) {
    int cu = (u < 4) ? (4 * tc + u) : (64 + 4 * tc + (u - 4));
    float s = acc[0][u] + acc[1][u] + acc[2][u] + acc[3][u];
    atomicAdd(&embA[cu], s);
  }
  __syncthreads();

#pragma unroll
  for (int v = 0; v < 4; ++v)
#pragma unroll
    for (int u = 0; u < 8; ++u) {
      int cu = (u < 4) ? (4 * tc + u) : (64 + 4 * tc + (u - 4));
      ldsX[cu * TS + 4 * tr + v] = acc[v][u];
    }
  __syncthreads();

  if (tid < 128) {
    int d = d0 + tid;
    if (d < DTOT) emb[(size_t)g * 1152 + d] = embA[tid] * (1.f / 128.f);
  }

  float gg[4][8];
#pragma unroll
  for (int v = 0; v < 4; ++v)
#pragma unroll
    for (int u = 0; u < 8; ++u) gg[v][u] = 0.f;
  for (int dl = 0; dl < NN; ++dl) {
    float4 a4v = *(const float4*)(ldsX + dl * TS + 4 * tr);
    float4 ba  = *(const float4*)(ldsX + dl * TS + 4 * tc);
    float4 bb  = *(const float4*)(ldsX + dl * TS + 64 + 4 * tc);
    float bv[8] = {ba.x, ba.y, ba.z, ba.w, bb.x, bb.y, bb.z, bb.w};
    float av[4] = {a4v.x, a4v.y, a4v.z, a4v.w};
#pragma unroll
    for (int v = 0; v < 4; ++v)
#pragma unroll
      for (int u = 0; u < 8; ++u) gg[v][u] = fmaf(av[v], bv[u], gg[v][u]);
  }
  float* Gc = Gp + ((size_t)c * 64 + g) * NN * NN;
#pragma unroll
  for (int v = 0; v < 4; ++v) {
    float4 lo = {gg[v][0], gg[v][1], gg[v][2], gg[v][3]};
    float4 hi = {gg[v][4], gg[v][5], gg[v][6], gg[v][7]};
    *(float4*)(Gc + (4 * tr + v) * NN + 4 * tc) = lo;
    *(float4*)(Gc + (4 * tr + v) * NN + 64 + 4 * tc) = hi;
  }
}

// ---------------------------------------------------------------------------
// KGRED (R25): dense G = sum_c Gp[c] on a FULL grid (1024 blocks, float4).
// ---------------------------------------------------------------------------
__global__ __launch_bounds__(256) void kgred(
    const float* __restrict__ Gp, float* __restrict__ G, int NCH) {
  const size_t cstride = (size_t)64 * NN * NN;
  size_t idx = ((size_t)blockIdx.x * 256 + threadIdx.x) * 4;
  float4 s = *(const float4*)(Gp + idx);
  for (int c = 1; c < NCH; ++c) {
    float4 v = *(const float4*)(Gp + c * cstride + idx);
    s.x += v.x; s.y += v.y; s.z += v.z; s.w += v.w;
  }
  *(float4*)(G + idx) = s;
}

// ---------------------------------------------------------------------------
// K45 (R22 form): blocks 0..63 = k4 (sp terms from dense G); 64..127 = k5a.
// ---------------------------------------------------------------------------
__global__ __launch_bounds__(256) void k45_fused(
    const float* __restrict__ G, double* __restrict__ spt,
    const float* __restrict__ emb, float* __restrict__ Dm, int DTOT) {
  __shared__ float inr[NN];
  __shared__ double red[4];
  const int bid = blockIdx.x, tid = threadIdx.x;
  if (bid < 64) {
    const int g = bid;
    const float* Gg = G + (size_t)g * NN * NN;
    if (tid < NN) {
      float n = sqrtf(fmaxf(Gg[tid * NN + tid], 0.f));
      inr[tid] = 1.f / fmaxf(n, 1e-12f);
    }
    __syncthreads();
    double s = 0.0;
    for (int e = tid; e < NN * NN; e += 256) {
      int i = e >> 7, j = e & 127;
      s += (double)(fabsf(Gg[e]) * inr[i] * inr[j]);
    }
    for (int off = 32; off; off >>= 1) s += __shfl_down(s, off);
    int wave = tid >> 6, lane = tid & 63;
    if (lane == 0) red[wave] = s;
    __syncthreads();
    if (tid == 0) spt[g] = -(red[0] + red[1] + red[2] + red[3]) / (double)(NN * NN);
  } else {
    const int i = bid - 64;
    const int wv = tid >> 6, l = tid & 63;
    float ei[18];
#pragma unroll
    for (int s = 0; s < 18; ++s) {
      int d = l + 64 * s;
      ei[s] = (d < DTOT) ? emb[(size_t)i * 1152 + d] : 0.f;
    }
    for (int jj = 0; jj < 16; ++jj) {
      int j = 4 * jj + wv;
      float acc = 0.f;
#pragma unroll
      for (int s = 0; s < 18; ++s) {
        int d = l + 64 * s;
        if (d < DTOT) {
          float df = ei[s] - emb[(size_t)j * 1152 + d];
          acc = fmaf(df, df, acc);
        }
      }
      for (int off = 32; off; off >>= 1) acc += __shfl_down(acc, off);
      if (l == 0) Dm[i * 64 + j] = (acc > 0.f) ? sqrtf(acc) : 0.f;
    }
  }
}

// ---------------------------------------------------------------------------
// K5b (R23): 4 waves, one class per wave; spt reduce on wave 0.
// ---------------------------------------------------------------------------
__global__ __launch_bounds__(256) void k5b_final(
    const float* __restrict__ Dm, const double* __restrict__ spt,
    const float* __restrict__ C, int NF,
    const int* __restrict__ ncls, float* __restrict__ out) {
  __shared__ double redH[8];     // per-wave {hl1, hl2}
  __shared__ double redS;
  const int tid = threadIdx.x;
  const int wv = tid >> 6, lane = tid & 63;
  const int nc = ncls[0];

  double hl1 = 0.0, hl2 = 0.0;
  const double beta = 1.0 / (double)nc + 1e-13;
  for (int cc = wv; cc < nc; cc += 4) {
    bool ip = (lane % nc) == cc;
    double ps = 0.0, ns = 0.0;
    for (int j = 0; j < 64; ++j) {
      double dv = (double)Dm[lane * 64 + j];
      bool jp = (j % nc) == cc;
      if (ip && jp) ps += dv;
      if (!ip && !jp) ns += dv;
    }
    for (int off = 32; off; off >>= 1) {
      ps += __shfl_down(ps, off);
      ns += __shfl_down(ns, off);
    }
    if (lane == 0) {
      int npos = 0;
      for (int q = 0; q < 64; ++q) if (q % nc == cc) npos++;
      int nneg = 64 - npos;
      hl2 += ps / ((double)npos * (double)npos);
      hl1 += -(ns / ((double)nneg * (double)nneg)) / beta;
    }
  }
  if (lane == 0) { redH[2 * wv] = hl1; redH[2 * wv + 1] = hl2; }

  if (wv == 0) {
    double spf = spt[lane] * exp(-((double)(64 - lane)) * log(64.0));
    for (int off = 32; off; off >>= 1) spf += __shfl_down(spf, off);
    if (lane == 0) redS = spf;
  }
  __syncthreads();

  if (tid == 0) {
    double h1 = redH[0] + redH[2] + redH[4] + redH[6];
    double h2 = redH[1] + redH[3] + redH[5] + redH[7];
    double l1 = 0.0, l2 = 0.0;
    for (int q = 0; q < NF; ++q) { double cv = (double)C[q]; l1 += fabs(cv); l2 += cv * cv; }
    l2 = sqrt(l2); if (l2 < 1e-12) l2 = 1e-12;
    double dims = sqrt((double)NF);
    double sc = (dims - l1 / l2) / (dims - 1.0);
    out[0] = (float)(sc + h2 + h1 + redS);
  }
}

// ---------------------------------------------------------------------------
extern "C" void kernel_launch(void* const* d_in, const int* in_sizes, int n_in,
                              void* d_out, int out_size, void* d_ws, size_t ws_size,
                              hipStream_t stream) {
  (void)n_in; (void)out_size;
  const float* x    = (const float*)d_in[0];
  const float* rs   = (const float*)d_in[1];
  const float* C    = (const float*)d_in[2];
  const int*   esrc = (const int*)d_in[3];
  const int*   edst = (const int*)d_in[4];
  const int*   ncls = (const int*)d_in[5];
  float* out = (float*)d_out;

  const int F0   = in_sizes[0] / (64 * 128);
  const int R    = in_sizes[1] / (64 * 128);
  const int NF   = in_sizes[2];
  const int E    = in_sizes[3] / 64;
  const int DTOT = F0 + R;
  const int NCH  = (DTOT + 127) / 128;   // 128-col chunks (fallback)
  const int NCH2 = (DTOT + 63) / 64;     // 64-col chunks (preferred)
  const float rscale = (float)(1.0 / sqrt((double)R));

  char* ws = (char*)d_ws;
  size_t off = 0;
  float*  L    = (float*)(ws + off);  off += (size_t)64 * NN * NN * 4;   // 4MB; reused as dense G
  float*  W    = (float*)(ws + off);  off += (size_t)64 * NN * NN * 4;   // 4MB
  // Gp overlays the L2d/L3d/L4d region (dead after k2) + extension.
  float*  Gp   = (float*)(ws + off);
  double* L2d  = (double*)(ws + off); off += (size_t)64 * NN * NN * 8;   // 8MB
  double* L3d  = (double*)(ws + off); off += (size_t)64 * NN * NN * 8;   // 8MB
  double* L4d  = (double*)(ws + off); off += (size_t)64 * NN * NN * 8;   // 8MB

  // decide chunking by available workspace
  const size_t tail_bytes = (size_t)64 * 1152 * 4 + 64 * 8 + 64 * 64 * 4 + 1024;
  const size_t have_pow   = (size_t)3 * 64 * NN * NN * 8;  // 24MB overlay
  size_t gp64  = (size_t)NCH2 * 64 * NN * NN * 4;          // 72MB
  size_t gp128 = (size_t)NCH  * 64 * NN * NN * 4;          // 36MB
  bool use64 = (off + (gp64 > have_pow ? gp64 - have_pow : 0) + tail_bytes) <= ws_size;
  size_t gp_bytes = use64 ? gp64 : gp128;
  if (gp_bytes > have_pow) off += gp_bytes - have_pow;

  float*  emb  = (float*)(ws + off);  off += (size_t)64 * 1152 * 4;
  double* spt  = (double*)(ws + off); off += (size_t)64 * 8;
  float*  Dm   = (float*)(ws + off);  off += (size_t)64 * 64 * 4;
  float*  G    = L;                   // dense G reuses L (dead after k2)

  hipMemsetAsync(W, 0, (size_t)64 * NN * NN * 4, stream);

  const int lds1 = (NN * SM + NN) * 4;             // 66560
  const int ldsf = NN * SF * 4;                    // 67584 (f32 staging)
  const int lds2 = 16 * RS * 8 + 8 * 16 * SS * 8 + 16 * SS * 8;  // 36480
  const int lds3 = (NN * TS + NN) * 4;             // 68096 (k3-128)
  const int lds364 = (128 * XS + 64) * 4;          // 35072 (k3-64) -> 4/CU
  hipFuncSetAttribute((const void*)k1_lap,    hipFuncAttributeMaxDynamicSharedMemorySize, lds1);
  hipFuncSetAttribute((const void*)kpow2,     hipFuncAttributeMaxDynamicSharedMemorySize, ldsf);
  hipFuncSetAttribute((const void*)kpow34,    hipFuncAttributeMaxDynamicSharedMemorySize, ldsf);
  hipFuncSetAttribute((const void*)k2_filter, hipFuncAttributeMaxDynamicSharedMemorySize, lds2);
  hipFuncSetAttribute((const void*)k3_fused,  hipFuncAttributeMaxDynamicSharedMemorySize, lds3);
  hipFuncSetAttribute((const void*)k3_fused64, hipFuncAttributeMaxDynamicSharedMemorySize, lds364);

  k1_lap<<<64, 256, lds1, stream>>>(esrc, edst, E, L);
  kpow2<<<512, 512, ldsf, stream>>>(L, L2d);
  kpow34<<<512, 512, ldsf, stream>>>(L, L2d, L3d, L4d);
  k2_filter<<<64 * NF, 512, lds2, stream>>>(L, L2d, L3d, L4d, C, NF, W);
  if (use64) {
    k3_fused64<<<64 * NCH2, 512, lds364, stream>>>(x, rs, W, Gp, emb, F0, R, DTOT, NCH2, rscale);
    kgred<<<1024, 256, 0, stream>>>(Gp, G, NCH2);
  } else {
    k3_fused<<<64 * NCH, 512, lds3, stream>>>(x, rs, W, Gp, emb, F0, R, DTOT, NCH, rscale);
    kgred<<<1024, 256, 0, stream>>>(Gp, G, NCH);
  }
  k45_fused<<<128, 256, 0, stream>>>(G, spt, emb, Dm, DTOT);
  k5b_final<<<1, 256, 0, stream>>>(Dm, spt, C, NF, ncls, out);
}

// Round 11
// 539.427 us; speedup vs baseline: 1.4456x; 1.0745x over previous
//
#include <hip/hip_runtime.h>
#include <math.h>

#define NN 128
#define SM 129   // padded LDS stride for 128-wide f32 tiles
#define TS 132   // k3-128 tile stride
#define RS 132   // row-panel stride (doubles)
#define SS 17    // per-wave scratch stride (doubles)
#define SF 132   // f32 staging stride (16B-aligned rows -> float4)
#define XS 68    // k3-64 X stride (128x68 f32 = 34.8KB)
#define YS 132   // k3-64 yT stride (64x132 f32 = 33.8KB, overlays X)

typedef double d4 __attribute__((ext_vector_type(4)));

// ---------------------------------------------------------------------------
// K1 (R17): build symmetric-normalized Laplacian per graph (f32) only.
// ---------------------------------------------------------------------------
__global__ __launch_bounds__(256) void k1_lap(
    const int* __restrict__ src, const int* __restrict__ dst,
    int E, float* __restrict__ Lout) {
  extern __shared__ float sm1[];            // A[128*129] + dinv[128]
  float* A    = sm1;
  float* dinv = sm1 + NN * SM;
  const int g   = blockIdx.x;
  const int tid = threadIdx.x;

  for (int e = tid; e < NN * NN; e += 256) {
    int i = e >> 7, j = e & 127;
    A[i * SM + j] = 0.f;
  }
  __syncthreads();
  const int* s = src + (size_t)g * E;
  const int* d = dst + (size_t)g * E;
  for (int e = tid; e < E; e += 256) {
    int a = s[e], b = d[e];
    A[a * SM + b] = 1.f;     // benign races: all write 1.0
    A[b * SM + a] = 1.f;
  }
  __syncthreads();
  if (tid < NN) {
    float acc = 0.f;
    for (int j = 0; j < NN; ++j) acc += A[tid * SM + j];
    dinv[tid] = (acc > 0.f) ? (float)(1.0 / sqrt((double)acc)) : 0.f;
  }
  __syncthreads();
  float* Lg = Lout + (size_t)g * NN * NN;
  for (int e = tid; e < NN * NN; e += 256) {
    int i = e >> 7, j = e & 127;
    Lg[e] = ((i == j) ? 1.f : 0.f) - dinv[i] * dinv[j] * A[i * SM + j];
  }
}

// ---------------------------------------------------------------------------
// KPOW2 (R22): L2 = L @ L. 512 blocks. L staged f32 in LDS. 2 blocks/CU.
// ---------------------------------------------------------------------------
__global__ __launch_bounds__(512, 4) void kpow2(
    const float* __restrict__ L, double* __restrict__ L2) {
  extern __shared__ float Bs[];             // 128 x 132 f32
  const int bid = blockIdx.x;
  const int g = bid >> 3, q = bid & 7;
  const int tid = threadIdx.x;
  const int wv = tid >> 6, ln = tid & 63;
  const int m  = ln & 15, kq = ln >> 4;
  const int rb = 16 * q;                    // row-band base
  const int cb = wv;                        // column tile

  int rIdx[4], cIdx[4];
  {
    d4 z = {0.0, 0.0, 0.0, 0.0};
    d4 pr = __builtin_amdgcn_mfma_f64_16x16x4f64((double)m, 1.0, z, 0, 0, 0);
    d4 pc = __builtin_amdgcn_mfma_f64_16x16x4f64(1.0, (double)m, z, 0, 0, 0);
#pragma unroll
    for (int r = 0; r < 4; ++r) {
      rIdx[r] = ((int)(pr[r] * 0.25 + 0.5)) & 15;
      cIdx[r] = ((int)(pc[r] * 0.25 + 0.5)) & 15;
    }
  }

  const float* Lg = L + (size_t)g * NN * NN;
  for (int e4 = tid; e4 < (NN * NN) / 4; e4 += 512) {
    int i = e4 >> 5, j4 = (e4 & 31) * 4;
    *(float4*)(Bs + i * SF + j4) = *(const float4*)(Lg + i * NN + j4);
  }
  __syncthreads();

  d4 acc = {0.0, 0.0, 0.0, 0.0};
  for (int kc = 0; kc < 32; ++kc) {
    double a = (double)Bs[(rb + m) * SF + 4 * kc + kq];
    double b = (double)Bs[(4 * kc + kq) * SF + 16 * cb + m];
    acc = __builtin_amdgcn_mfma_f64_16x16x4f64(a, b, acc, 0, 0, 0);
  }
  double* out = L2 + (size_t)g * NN * NN;
#pragma unroll
  for (int r = 0; r < 4; ++r)
    out[(rb + rIdx[r]) * NN + 16 * cb + cIdx[r]] = acc[r];
}

// ---------------------------------------------------------------------------
// KPOW34 (R22): 512 blocks = g(6b) x quarter(2b) x job(1b).
// ---------------------------------------------------------------------------
__global__ __launch_bounds__(512, 4) void kpow34(
    const float* __restrict__ L, const double* __restrict__ L2,
    double* __restrict__ L3, double* __restrict__ L4) {
  extern __shared__ float Bs[];             // 128 x 132 f32 (job0 only)
  const int bid = blockIdx.x;
  const int g = bid >> 3, q = (bid >> 1) & 3, job = bid & 1;
  const int tid = threadIdx.x;
  const int wv = tid >> 6, ln = tid & 63;
  const int m  = ln & 15, kq = ln >> 4;
  const int rb = 32 * q + 16 * (wv & 1);
  const int cb0 = 2 * (wv >> 1);

  int rIdx[4], cIdx[4];
  {
    d4 z = {0.0, 0.0, 0.0, 0.0};
    d4 pr = __builtin_amdgcn_mfma_f64_16x16x4f64((double)m, 1.0, z, 0, 0, 0);
    d4 pc = __builtin_amdgcn_mfma_f64_16x16x4f64(1.0, (double)m, z, 0, 0, 0);
#pragma unroll
    for (int r = 0; r < 4; ++r) {
      rIdx[r] = ((int)(pr[r] * 0.25 + 0.5)) & 15;
      cIdx[r] = ((int)(pc[r] * 0.25 + 0.5)) & 15;
    }
  }

  const float*  Lg  = L  + (size_t)g * NN * NN;
  const double* L2g = L2 + (size_t)g * NN * NN;
  if (job == 0) {
    for (int e4 = tid; e4 < (NN * NN) / 4; e4 += 512) {
      int i = e4 >> 5, j4 = (e4 & 31) * 4;
      *(float4*)(Bs + i * SF + j4) = *(const float4*)(Lg + i * NN + j4);
    }
  }
  __syncthreads();

  d4 acc[2];
#pragma unroll
  for (int c = 0; c < 2; ++c) {
    acc[c][0] = 0.0; acc[c][1] = 0.0; acc[c][2] = 0.0; acc[c][3] = 0.0;
  }
  if (job == 0) {
    for (int kc = 0; kc < 32; ++kc) {
      double a = L2g[(rb + m) * NN + 4 * kc + kq];
#pragma unroll
      for (int c = 0; c < 2; ++c) {
        double b = (double)Bs[(4 * kc + kq) * SF + 16 * (cb0 + c) + m];
        acc[c] = __builtin_amdgcn_mfma_f64_16x16x4f64(a, b, acc[c], 0, 0, 0);
      }
    }
  } else {
    for (int kc = 0; kc < 32; ++kc) {
      double a = L2g[(rb + m) * NN + 4 * kc + kq];
#pragma unroll
      for (int c = 0; c < 2; ++c) {
        double b = L2g[(4 * kc + kq) * NN + 16 * (cb0 + c) + m];
        acc[c] = __builtin_amdgcn_mfma_f64_16x16x4f64(a, b, acc[c], 0, 0, 0);
      }
    }
  }
  double* out = (job == 0 ? L3 : L4) + (size_t)g * NN * NN;
#pragma unroll
  for (int c = 0; c < 2; ++c)
#pragma unroll
    for (int r = 0; r < 4; ++r)
      out[(rb + rIdx[r]) * NN + 16 * (cb0 + c) + cIdx[r]] = acc[c][r];
}

// ---------------------------------------------------------------------------
// K2 (R14 exact, FROZEN): algebraic assembly + blocked GJ with serial-Pi.
// 268us stable; VGPR 64 + 64 AGPR = full 128 budget at (512,4).
// R18/R19/R21 restructurings ALL spilled to scratch. DO NOT MODIFY.
// ---------------------------------------------------------------------------
__global__ __launch_bounds__(512, 4) void k2_filter(
    const float* __restrict__ L, const double* __restrict__ L2,
    const double* __restrict__ L3, const double* __restrict__ L4,
    const float* __restrict__ C, int NF, float* __restrict__ W) {
  extern __shared__ char smraw[];
  double* Rp  = (double*)smraw;                      // row panel 16x132
  double* Scd = (double*)(smraw + 16 * RS * 8);      // 8 wave scratches 16x17
  double* Pv  = (double*)(smraw + 16 * RS * 8 + 8 * 16 * SS * 8); // Pi 16x17

  const int bid = blockIdx.x;
  const int g = bid / NF, f = bid % NF;
  const int tid = threadIdx.x;
  const int wv = tid >> 6, ln = tid & 63;
  const int m  = ln & 15, kq = ln >> 4;
  double* S = Scd + wv * 16 * SS;

  double csum = 0.0;
  for (int q = 0; q < NF; ++q) { double c = (double)C[q]; csum += c * c; }
  double cn = sqrt(csum); if (cn < 1e-12) cn = 1e-12;
  const double a4 = 6.25e-6;                         // (STEP/2)^4
  const double coef = 1.4142135623730951 * a4 * ((double)C[f] / cn);
  const float  bf = (float)((double)f * 0.1);
  const double bb = (double)bf;
  const double c3 = -4.0 * bb;
  const double c2 = 6.0 * bb * bb;
  const double c1 = -4.0 * bb * bb * bb;
  const double c0 = bb * bb * bb * bb + a4;

  int rIdx[4], cIdx[4];
  {
    d4 z = {0.0, 0.0, 0.0, 0.0};
    d4 pr = __builtin_amdgcn_mfma_f64_16x16x4f64((double)m, 1.0, z, 0, 0, 0);
    d4 pc = __builtin_amdgcn_mfma_f64_16x16x4f64(1.0, (double)m, z, 0, 0, 0);
#pragma unroll
    for (int r = 0; r < 4; ++r) {
      rIdx[r] = ((int)(pr[r] * 0.25 + 0.5)) & 15;
      cIdx[r] = ((int)(pc[r] * 0.25 + 0.5)) & 15;
    }
  }

  // phase A: assemble T (D-layout) from the power matrices -- pure n^2
  const float*  Lg  = L  + (size_t)g * NN * NN;
  const double* L2g = L2 + (size_t)g * NN * NN;
  const double* L3g = L3 + (size_t)g * NN * NN;
  const double* L4g = L4 + (size_t)g * NN * NN;
  d4 T[8];
#pragma unroll
  for (int cb = 0; cb < 8; ++cb)
#pragma unroll
    for (int r = 0; r < 4; ++r) {
      int i = 16 * wv + rIdx[r], j = 16 * cb + cIdx[r];
      int idx = i * NN + j;
      double v = L4g[idx];
      v = fma(c3, L3g[idx], v);
      v = fma(c2, L2g[idx], v);
      v = fma(c1, (double)Lg[idx], v);
      if (i == j) v += c0;
      T[cb][r] = v;
    }

  // phase 4: blocked GJ, 8 steps, 3 block-barriers each, NOT unrolled
#pragma unroll 1
  for (int t = 0; t < 8; ++t) {
    if (wv == t) {
#pragma unroll
      for (int cb = 0; cb < 8; ++cb)
#pragma unroll
        for (int r = 0; r < 4; ++r)
          Rp[rIdx[r] * RS + 16 * cb + cIdx[r]] = T[cb][r];
    }
    __syncthreads();                                 // B1 (Rp visible)

    if (wv == t) {
      double sr[4];
#pragma unroll
      for (int r = 0; r < 4; ++r) sr[r] = Rp[(4 * r + kq) * RS + 16 * t + m];
#pragma unroll
      for (int k = 0; k < 16; ++k) {
        const int kr = k >> 2, kl = k & 3;
        double pv   = __shfl(sr[kr], 16 * kl + k);
        double rowv = __shfl(sr[kr], 16 * kl + m);
        double cv[4];
#pragma unroll
        for (int r = 0; r < 4; ++r) cv[r] = __shfl(sr[r], 16 * kq + k);
        double dp = 1.0 / pv;
#pragma unroll
        for (int r = 0; r < 4; ++r) {
          int i = 4 * r + kq;
          double nv;
          if (i == k)      nv = (m == k) ? dp : rowv * dp;
          else if (m == k) nv = -cv[r] * dp;
          else             nv = fma(-(cv[r] * dp), rowv, sr[r]);
          sr[r] = nv;
        }
      }
#pragma unroll
      for (int r = 0; r < 4; ++r) Pv[(4 * r + kq) * SS + m] = sr[r];
    }
    __syncthreads();                                 // B2 (Pi visible)

#pragma unroll
    for (int cb = 0; cb < 8; ++cb) {
      if (cb != t) continue;
      if (wv == t) {
#pragma unroll
        for (int r = 0; r < 4; ++r) T[cb][r] = Pv[rIdx[r] * SS + cIdx[r]];
      } else {
#pragma unroll
        for (int r = 0; r < 4; ++r) S[rIdx[r] * SS + cIdx[r]] = T[cb][r];
        __builtin_amdgcn_wave_barrier();
        d4 ncv = {0.0, 0.0, 0.0, 0.0};
#pragma unroll
        for (int kc = 0; kc < 4; ++kc) {
          double a = S[m * SS + 4 * kc + kq];
          double b = -Pv[(4 * kc + kq) * SS + m];
          ncv = __builtin_amdgcn_mfma_f64_16x16x4f64(a, b, ncv, 0, 0, 0);
        }
        T[cb] = ncv;
        __builtin_amdgcn_wave_barrier();
#pragma unroll
        for (int r = 0; r < 4; ++r) S[rIdx[r] * SS + cIdx[r]] = T[cb][r];
      }
    }
    __builtin_amdgcn_wave_barrier();

    const double* asrc = (wv == t) ? Pv : S;
#pragma unroll
    for (int cb = 0; cb < 8; ++cb) {
      if (cb == t) continue;
      d4 acc;
      if (wv == t) { acc[0] = 0.0; acc[1] = 0.0; acc[2] = 0.0; acc[3] = 0.0; }
      else         { acc = T[cb]; }
#pragma unroll
      for (int kc = 0; kc < 4; ++kc) {
        double a = asrc[m * SS + 4 * kc + kq];
        double b = Rp[(4 * kc + kq) * RS + 16 * cb + m];
        acc = __builtin_amdgcn_mfma_f64_16x16x4f64(a, b, acc, 0, 0, 0);
      }
      T[cb] = acc;
    }
    __syncthreads();                                 // B3 (Rp/Pv reads done)
  }

  // phase 5: W += coef * K^{-1}
  float* Wg = W + (size_t)g * NN * NN;
#pragma unroll
  for (int cb = 0; cb < 8; ++cb)
#pragma unroll
    for (int r = 0; r < 4; ++r)
      atomicAdd(&Wg[(16 * wv + rIdx[r]) * NN + 16 * cb + cIdx[r]],
                (float)(coef * T[cb][r]));
}

// ---------------------------------------------------------------------------
// K3-64 (R27): 64-col chunks -> LDS 35KB -> 4 blocks/CU (32 waves, max occ).
// ---------------------------------------------------------------------------
__global__ __launch_bounds__(512, 8) void k3_fused64(
    const float* __restrict__ x, const float* __restrict__ rs,
    const float* __restrict__ W, float* __restrict__ Gp,
    float* __restrict__ emb, int F0, int R, int DTOT, int NCH2,
    float rscale) {
  extern __shared__ float sm3[];
  float* ldsX = sm3;                 // [128][68] X, then [64][132] yT in place
  float* embA = sm3 + 128 * XS;      // 64 f32 emb accumulator
  const int bid = blockIdx.x;
  const int g = bid / NCH2;
  const int c = bid % NCH2;
  const int d0 = c * 64;
  const int tid = threadIdx.x, tr = tid >> 4, tc = tid & 15;

  const float* xg = x + (size_t)g * NN * F0;
  const float* rg = rs + (size_t)g * NN * R;
  for (int e = tid; e < NN * 64; e += 512) {
    int k = e >> 6, dl = e & 63;
    int d = d0 + dl;
    float v = 0.f;
    if (d < DTOT) v = (d < F0) ? xg[k * F0 + d] : rg[k * R + (d - F0)] * rscale;
    ldsX[k * XS + dl] = v;
  }
  if (tid < 64) embA[tid] = 0.f;
  __syncthreads();

  // GEMM1: y = X - W@X. Thread: rows 4tr+v, cols 4tc+u (within chunk).
  const float* Wg = W + (size_t)g * NN * NN;
  float acc[4][4];
#pragma unroll
  for (int v = 0; v < 4; ++v)
#pragma unroll
    for (int u = 0; u < 4; ++u) acc[v][u] = 0.f;
  float4 w4 = *(const float4*)(Wg + 4 * tr);
  for (int k = 0; k < NN; ++k) {
    float4 w4n;
    if (k < NN - 1) w4n = *(const float4*)(Wg + (k + 1) * NN + 4 * tr);
    float4 xa = *(const float4*)(ldsX + k * XS + 4 * tc);  // 2-way, free
    float xv[4] = {xa.x, xa.y, xa.z, xa.w};
    float wvv[4] = {w4.x, w4.y, w4.z, w4.w};
#pragma unroll
    for (int v = 0; v < 4; ++v)
#pragma unroll
      for (int u = 0; u < 4; ++u) acc[v][u] = fmaf(wvv[v], xv[u], acc[v][u]);
    w4 = w4n;
  }
  // y = X - (W@X)
#pragma unroll
  for (int v = 0; v < 4; ++v) {
    float4 sa = *(const float4*)(ldsX + (4 * tr + v) * XS + 4 * tc);
    acc[v][0] = sa.x - acc[v][0]; acc[v][1] = sa.y - acc[v][1];
    acc[v][2] = sa.z - acc[v][2]; acc[v][3] = sa.w - acc[v][3];
  }

  // emb partials: column sums via LDS atomics
#pragma unroll
  for (int u = 0; u < 4; ++u) {
    float s = acc[0][u] + acc[1][u] + acc[2][u] + acc[3][u];
    atomicAdd(&embA[4 * tc + u], s);
  }
  __syncthreads();                 // all X reads + embA adds complete

  // yT [64][132] in place over the dead X buffer (once per block)
#pragma unroll
  for (int v = 0; v < 4; ++v)
#pragma unroll
    for (int u = 0; u < 4; ++u)
      ldsX[(4 * tc + u) * YS + 4 * tr + v] = acc[v][u];
  __syncthreads();

  if (tid < 64) {
    int d = d0 + tid;
    if (d < DTOT) emb[(size_t)g * 1152 + d] = embA[tid] * (1.f / 128.f);
  }

  // GEMM2: G[i][j] += sum_{d in chunk} y[i,d]*y[j,d]; depth 64.
  float gg[4][8];
#pragma unroll
  for (int v = 0; v < 4; ++v)
#pragma unroll
    for (int u = 0; u < 8; ++u) gg[v][u] = 0.f;
  for (int dl = 0; dl < 64; ++dl) {
    float4 a4v = *(const float4*)(ldsX + dl * YS + 4 * tr);      // broadcast
    float4 ba  = *(const float4*)(ldsX + dl * YS + 4 * tc);      // 2-way
    float4 bb  = *(const float4*)(ldsX + dl * YS + 64 + 4 * tc); // 2-way
    float bv[8] = {ba.x, ba.y, ba.z, ba.w, bb.x, bb.y, bb.z, bb.w};
    float av[4] = {a4v.x, a4v.y, a4v.z, a4v.w};
#pragma unroll
    for (int v = 0; v < 4; ++v)
#pragma unroll
      for (int u = 0; u < 8; ++u) gg[v][u] = fmaf(av[v], bv[u], gg[v][u]);
  }
  float* Gc = Gp + ((size_t)c * 64 + g) * NN * NN;
#pragma unroll
  for (int v = 0; v < 4; ++v) {
    float4 lo = {gg[v][0], gg[v][1], gg[v][2], gg[v][3]};
    float4 hi = {gg[v][4], gg[v][5], gg[v][6], gg[v][7]};
    *(float4*)(Gc + (4 * tr + v) * NN + 4 * tc) = lo;
    *(float4*)(Gc + (4 * tr + v) * NN + 64 + 4 * tc) = hi;
  }
}

// ---------------------------------------------------------------------------
// K3-128 (R26, fallback if workspace too small for 18 Gp partials).
// ---------------------------------------------------------------------------
__global__ __launch_bounds__(512, 4) void k3_fused(
    const float* __restrict__ x, const float* __restrict__ rs,
    const float* __restrict__ W, float* __restrict__ Gp,
    float* __restrict__ emb, int F0, int R, int DTOT, int NCH,
    float rscale) {
  extern __shared__ float sm3[];
  float* ldsX = sm3;                 // 128*132 f32: X, later yT (in place)
  float* embA = sm3 + NN * TS;       // 128 f32 emb accumulator
  const int bid = blockIdx.x;
  const int g = bid / NCH;
  const int c = bid % NCH;
  const int d0 = c * 128;
  const int tid = threadIdx.x, tr = tid >> 4, tc = tid & 15;

  const float* xg = x + (size_t)g * NN * F0;
  const float* rg = rs + (size_t)g * NN * R;
  for (int e = tid; e < NN * NN; e += 512) {
    int k = e >> 7, dl = e & 127;
    int d = d0 + dl;
    float v = 0.f;
    if (d < DTOT) v = (d < F0) ? xg[k * F0 + d] : rg[k * R + (d - F0)] * rscale;
    ldsX[k * TS + dl] = v;
  }
  if (tid < NN) embA[tid] = 0.f;
  __syncthreads();

  const float* Wg = W + (size_t)g * NN * NN;
  float acc[4][8];
#pragma unroll
  for (int v = 0; v < 4; ++v)
#pragma unroll
    for (int u = 0; u < 8; ++u) acc[v][u] = 0.f;
  float4 w4 = *(const float4*)(Wg + 4 * tr);
  for (int k = 0; k < NN; ++k) {
    float4 w4n;
    if (k < NN - 1) w4n = *(const float4*)(Wg + (k + 1) * NN + 4 * tr);
    float4 xa = *(const float4*)(ldsX + k * TS + 4 * tc);
    float4 xb = *(const float4*)(ldsX + k * TS + 64 + 4 * tc);
    float xv[8] = {xa.x, xa.y, xa.z, xa.w, xb.x, xb.y, xb.z, xb.w};
    float wvv[4] = {w4.x, w4.y, w4.z, w4.w};
#pragma unroll
    for (int v = 0; v < 4; ++v)
#pragma unroll
      for (int u = 0; u < 8; ++u) acc[v][u] = fmaf(wvv[v], xv[u], acc[v][u]);
    w4 = w4n;
  }
#pragma unroll
  for (int v = 0; v < 4; ++v) {
    float4 sa = *(const float4*)(ldsX + (4 * tr + v) * TS + 4 * tc);
    float4 sb = *(const float4*)(ldsX + (4 * tr + v) * TS + 64 + 4 * tc);
    acc[v][0] = sa.x - acc[v][0]; acc[v][1] = sa.y - acc[v][1];
    acc[v][2] = sa.z - acc[v][2]; acc[v][3] = sa.w - acc[v][3];
    acc[v][4] = sb.x - acc[v][4]; acc[v][5] = sb.y - acc[v][5];
    acc[v][6] = sb.z - acc[v][6]; acc[v][7] = sb.w - acc[v][7];
  }

#pragma unroll
  for (int u = 0; u < 8; ++u) {
    int cu = (u < 4) ? (4 * tc + u) : (64 + 4 * tc + (u - 4));
    float s = acc[0][u] + acc[1][u] + acc[2][u] + acc[3][u];
    atomicAdd(&embA[cu], s);
  }
  __syncthreads();

#pragma unroll
  for (int v = 0; v < 4; ++v)
#pragma unroll
    for (int u = 0; u < 8; ++u) {
      int cu = (u < 4) ? (4 * tc + u) : (64 + 4 * tc + (u - 4));
      ldsX[cu * TS + 4 * tr + v] = acc[v][u];
    }
  __syncthreads();

  if (tid < 128) {
    int d = d0 + tid;
    if (d < DTOT) emb[(size_t)g * 1152 + d] = embA[tid] * (1.f / 128.f);
  }

  float gg[4][8];
#pragma unroll
  for (int v = 0; v < 4; ++v)
#pragma unroll
    for (int u = 0; u < 8; ++u) gg[v][u] = 0.f;
  for (int dl = 0; dl < NN; ++dl) {
    float4 a4v = *(const float4*)(ldsX + dl * TS + 4 * tr);
    float4 ba  = *(const float4*)(ldsX + dl * TS + 4 * tc);
    float4 bb  = *(const float4*)(ldsX + dl * TS + 64 + 4 * tc);
    float bv[8] = {ba.x, ba.y, ba.z, ba.w, bb.x, bb.y, bb.z, bb.w};
    float av[4] = {a4v.x, a4v.y, a4v.z, a4v.w};
#pragma unroll
    for (int v = 0; v < 4; ++v)
#pragma unroll
      for (int u = 0; u < 8; ++u) gg[v][u] = fmaf(av[v], bv[u], gg[v][u]);
  }
  float* Gc = Gp + ((size_t)c * 64 + g) * NN * NN;
#pragma unroll
  for (int v = 0; v < 4; ++v) {
    float4 lo = {gg[v][0], gg[v][1], gg[v][2], gg[v][3]};
    float4 hi = {gg[v][4], gg[v][5], gg[v][6], gg[v][7]};
    *(float4*)(Gc + (4 * tr + v) * NN + 4 * tc) = lo;
    *(float4*)(Gc + (4 * tr + v) * NN + 64 + 4 * tc) = hi;
  }
}

// ---------------------------------------------------------------------------
// KGRED (R25): dense G = sum_c Gp[c] on a FULL grid (1024 blocks, float4).
// ---------------------------------------------------------------------------
__global__ __launch_bounds__(256) void kgred(
    const float* __restrict__ Gp, float* __restrict__ G, int NCH) {
  const size_t cstride = (size_t)64 * NN * NN;
  size_t idx = ((size_t)blockIdx.x * 256 + threadIdx.x) * 4;
  float4 s = *(const float4*)(Gp + idx);
  for (int c = 1; c < NCH; ++c) {
    float4 v = *(const float4*)(Gp + c * cstride + idx);
    s.x += v.x; s.y += v.y; s.z += v.z; s.w += v.w;
  }
  *(float4*)(G + idx) = s;
}

// ---------------------------------------------------------------------------
// K45 (R28): full-machine parallelism for both phases.
// Blocks 0..255  = k4 partials (4 per graph, 32-row quarter each; f64
//                  atomicAdd of the partial into spt[g]; scaling -> k5b).
// Blocks 256..383 = k5a cdist (2 per row i, half the j range each).
// Was 64+64 starved blocks (25% machine).
// ---------------------------------------------------------------------------
__global__ __launch_bounds__(256) void k45_fused(
    const float* __restrict__ G, double* __restrict__ spt,
    const float* __restrict__ emb, float* __restrict__ Dm, int DTOT) {
  __shared__ float inr[NN];
  __shared__ double red[4];
  const int bid = blockIdx.x, tid = threadIdx.x;
  if (bid < 256) {
    const int g = bid >> 2, qt = bid & 3;
    const float* Gg = G + (size_t)g * NN * NN;
    if (tid < NN) {
      float n = sqrtf(fmaxf(Gg[tid * NN + tid], 0.f));
      inr[tid] = 1.f / fmaxf(n, 1e-12f);
    }
    __syncthreads();
    double s = 0.0;
    const int base = qt * 4096;                 // 32-row quarter
    for (int e0 = tid; e0 < 4096; e0 += 256) {
      int e = base + e0;
      int i = e >> 7, j = e & 127;
      s += (double)(fabsf(Gg[e]) * inr[i] * inr[j]);
    }
    for (int off = 32; off; off >>= 1) s += __shfl_down(s, off);
    int wave = tid >> 6, lane = tid & 63;
    if (lane == 0) red[wave] = s;
    __syncthreads();
    if (tid == 0) atomicAdd(&spt[g], red[0] + red[1] + red[2] + red[3]);
  } else {
    const int ii = bid - 256;
    const int i = ii >> 1, h = ii & 1;          // row i, j-half h
    const int wv = tid >> 6, l = tid & 63;
    float ei[18];
#pragma unroll
    for (int s = 0; s < 18; ++s) {
      int d = l + 64 * s;
      ei[s] = (d < DTOT) ? emb[(size_t)i * 1152 + d] : 0.f;
    }
    for (int jj = 8 * h; jj < 8 * h + 8; ++jj) {
      int j = 4 * jj + wv;
      float acc = 0.f;
#pragma unroll
      for (int s = 0; s < 18; ++s) {
        int d = l + 64 * s;
        if (d < DTOT) {
          float df = ei[s] - emb[(size_t)j * 1152 + d];
          acc = fmaf(df, df, acc);
        }
      }
      for (int off = 32; off; off >>= 1) acc += __shfl_down(acc, off);
      if (l == 0) Dm[i * 64 + j] = (acc > 0.f) ? sqrtf(acc) : 0.f;
    }
  }
}

// ---------------------------------------------------------------------------
// K5b (R28): 4 waves, one class per wave; spt now holds the raw |.|-sum
// (k4 scaling -(.)/n^2 applied here).
// ---------------------------------------------------------------------------
__global__ __launch_bounds__(256) void k5b_final(
    const float* __restrict__ Dm, const double* __restrict__ spt,
    const float* __restrict__ C, int NF,
    const int* __restrict__ ncls, float* __restrict__ out) {
  __shared__ double redH[8];     // per-wave {hl1, hl2}
  __shared__ double redS;
  const int tid = threadIdx.x;
  const int wv = tid >> 6, lane = tid & 63;
  const int nc = ncls[0];

  double hl1 = 0.0, hl2 = 0.0;
  const double beta = 1.0 / (double)nc + 1e-13;
  for (int cc = wv; cc < nc; cc += 4) {
    bool ip = (lane % nc) == cc;
    double ps = 0.0, ns = 0.0;
    for (int j = 0; j < 64; ++j) {
      double dv = (double)Dm[lane * 64 + j];
      bool jp = (j % nc) == cc;
      if (ip && jp) ps += dv;
      if (!ip && !jp) ns += dv;
    }
    for (int off = 32; off; off >>= 1) {
      ps += __shfl_down(ps, off);
      ns += __shfl_down(ns, off);
    }
    if (lane == 0) {
      int npos = 0;
      for (int q = 0; q < 64; ++q) if (q % nc == cc) npos++;
      int nneg = 64 - npos;
      hl2 += ps / ((double)npos * (double)npos);
      hl1 += -(ns / ((double)nneg * (double)nneg)) / beta;
    }
  }
  if (lane == 0) { redH[2 * wv] = hl1; redH[2 * wv + 1] = hl2; }

  if (wv == 0) {
    double sp = -spt[lane] * (1.0 / (double)(NN * NN));   // k4 scaling
    double spf = sp * exp(-((double)(64 - lane)) * log(64.0));
    for (int off = 32; off; off >>= 1) spf += __shfl_down(spf, off);
    if (lane == 0) redS = spf;
  }
  __syncthreads();

  if (tid == 0) {
    double h1 = redH[0] + redH[2] + redH[4] + redH[6];
    double h2 = redH[1] + redH[3] + redH[5] + redH[7];
    double l1 = 0.0, l2 = 0.0;
    for (int q = 0; q < NF; ++q) { double cv = (double)C[q]; l1 += fabs(cv); l2 += cv * cv; }
    l2 = sqrt(l2); if (l2 < 1e-12) l2 = 1e-12;
    double dims = sqrt((double)NF);
    double sc = (dims - l1 / l2) / (dims - 1.0);
    out[0] = (float)(sc + h2 + h1 + redS);
  }
}

// ---------------------------------------------------------------------------
extern "C" void kernel_launch(void* const* d_in, const int* in_sizes, int n_in,
                              void* d_out, int out_size, void* d_ws, size_t ws_size,
                              hipStream_t stream) {
  (void)n_in; (void)out_size;
  const float* x    = (const float*)d_in[0];
  const float* rs   = (const float*)d_in[1];
  const float* C    = (const float*)d_in[2];
  const int*   esrc = (const int*)d_in[3];
  const int*   edst = (const int*)d_in[4];
  const int*   ncls = (const int*)d_in[5];
  float* out = (float*)d_out;

  const int F0   = in_sizes[0] / (64 * 128);
  const int R    = in_sizes[1] / (64 * 128);
  const int NF   = in_sizes[2];
  const int E    = in_sizes[3] / 64;
  const int DTOT = F0 + R;
  const int NCH  = (DTOT + 127) / 128;   // 128-col chunks (fallback)
  const int NCH2 = (DTOT + 63) / 64;     // 64-col chunks (preferred)
  const float rscale = (float)(1.0 / sqrt((double)R));

  char* ws = (char*)d_ws;
  size_t off = 0;
  float*  L    = (float*)(ws + off);  off += (size_t)64 * NN * NN * 4;   // 4MB; reused as dense G
  float*  W    = (float*)(ws + off);  off += (size_t)64 * NN * NN * 4;   // 4MB
  // Gp overlays the L2d/L3d/L4d region (dead after k2) + extension.
  float*  Gp   = (float*)(ws + off);
  double* L2d  = (double*)(ws + off); off += (size_t)64 * NN * NN * 8;   // 8MB
  double* L3d  = (double*)(ws + off); off += (size_t)64 * NN * NN * 8;   // 8MB
  double* L4d  = (double*)(ws + off); off += (size_t)64 * NN * NN * 8;   // 8MB

  // decide chunking by available workspace
  const size_t tail_bytes = (size_t)64 * 1152 * 4 + 64 * 8 + 64 * 64 * 4 + 1024;
  const size_t have_pow   = (size_t)3 * 64 * NN * NN * 8;  // 24MB overlay
  size_t gp64  = (size_t)NCH2 * 64 * NN * NN * 4;          // 72MB
  size_t gp128 = (size_t)NCH  * 64 * NN * NN * 4;          // 36MB
  bool use64 = (off + (gp64 > have_pow ? gp64 - have_pow : 0) + tail_bytes) <= ws_size;
  size_t gp_bytes = use64 ? gp64 : gp128;
  if (gp_bytes > have_pow) off += gp_bytes - have_pow;

  float*  emb  = (float*)(ws + off);  off += (size_t)64 * 1152 * 4;
  double* spt  = (double*)(ws + off); off += (size_t)64 * 8;
  float*  Dm   = (float*)(ws + off);  off += (size_t)64 * 64 * 4;
  float*  G    = L;                   // dense G reuses L (dead after k2)

  hipMemsetAsync(W, 0, (size_t)64 * NN * NN * 4, stream);
  hipMemsetAsync(spt, 0, (size_t)64 * 8, stream);   // k4 partials accumulate

  const int lds1 = (NN * SM + NN) * 4;             // 66560
  const int ldsf = NN * SF * 4;                    // 67584 (f32 staging)
  const int lds2 = 16 * RS * 8 + 8 * 16 * SS * 8 + 16 * SS * 8;  // 36480
  const int lds3 = (NN * TS + NN) * 4;             // 68096 (k3-128)
  const int lds364 = (128 * XS + 64) * 4;          // 35072 (k3-64) -> 4/CU
  hipFuncSetAttribute((const void*)k1_lap,    hipFuncAttributeMaxDynamicSharedMemorySize, lds1);
  hipFuncSetAttribute((const void*)kpow2,     hipFuncAttributeMaxDynamicSharedMemorySize, ldsf);
  hipFuncSetAttribute((const void*)kpow34,    hipFuncAttributeMaxDynamicSharedMemorySize, ldsf);
  hipFuncSetAttribute((const void*)k2_filter, hipFuncAttributeMaxDynamicSharedMemorySize, lds2);
  hipFuncSetAttribute((const void*)k3_fused,  hipFuncAttributeMaxDynamicSharedMemorySize, lds3);
  hipFuncSetAttribute((const void*)k3_fused64, hipFuncAttributeMaxDynamicSharedMemorySize, lds364);

  k1_lap<<<64, 256, lds1, stream>>>(esrc, edst, E, L);
  kpow2<<<512, 512, ldsf, stream>>>(L, L2d);
  kpow34<<<512, 512, ldsf, stream>>>(L, L2d, L3d, L4d);
  k2_filter<<<64 * NF, 512, lds2, stream>>>(L, L2d, L3d, L4d, C, NF, W);
  if (use64) {
    k3_fused64<<<64 * NCH2, 512, lds364, stream>>>(x, rs, W, Gp, emb, F0, R, DTOT, NCH2, rscale);
    kgred<<<1024, 256, 0, stream>>>(Gp, G, NCH2);
  } else {
    k3_fused<<<64 * NCH, 512, lds3, stream>>>(x, rs, W, Gp, emb, F0, R, DTOT, NCH, rscale);
    kgred<<<1024, 256, 0, stream>>>(Gp, G, NCH);
  }
  k45_fused<<<384, 256, 0, stream>>>(G, spt, emb, Dm, DTOT);
  k5b_final<<<1, 256, 0, stream>>>(Dm, spt, C, NF, ncls, out);
}